// Round 2
// baseline (117.680 us; speedup 1.0000x reference)
//
#include <hip/hip_runtime.h>
#include <math.h>

// Tensor-train log-likelihood, B=256, T=1024, d=4, D=32.
// Strategy: precompute all 4^4 = 256 quad matrix products (pre-scaled by
// exact powers of two), then run 256 chain steps per sequence with one
// wavefront per sequence.

#define TT_B 256
#define TT_T 1024

// Quad table: [m][k(0..3)][lane(0..63)][c(0..3)] floats = 4KB per matrix.
// Element (m,k,lane,c) = Qs_m[16*(lane>>5) + 4k + c][lane&31], where
// Qs_m = Q_m * 2^-kQ[m].
__device__ float g_QTP[256 * 1024];
__device__ int   g_kQ[256];

// C[i][j] for i = 16h+r (r=0..15): c[r] = sum_k AT[k][16h+r] * B[k][j]
// AT has row stride 36 floats (16B-aligned rows, pad kills write conflicts),
// B has row stride 32.
__device__ __forceinline__ void mm32(const float* __restrict__ AT,
                                     const float* __restrict__ B,
                                     int h, int j, float c[16])
{
#pragma unroll
    for (int r = 0; r < 16; ++r) c[r] = 0.f;
#pragma unroll 4
    for (int k = 0; k < 32; ++k) {
        float bv = B[k * 32 + j];
        const float4* ar = (const float4*)(AT + k * 36 + 16 * h);
        float4 a0 = ar[0], a1 = ar[1], a2 = ar[2], a3 = ar[3];
        c[ 0] = fmaf(a0.x, bv, c[ 0]); c[ 1] = fmaf(a0.y, bv, c[ 1]);
        c[ 2] = fmaf(a0.z, bv, c[ 2]); c[ 3] = fmaf(a0.w, bv, c[ 3]);
        c[ 4] = fmaf(a1.x, bv, c[ 4]); c[ 5] = fmaf(a1.y, bv, c[ 5]);
        c[ 6] = fmaf(a1.z, bv, c[ 6]); c[ 7] = fmaf(a1.w, bv, c[ 7]);
        c[ 8] = fmaf(a2.x, bv, c[ 8]); c[ 9] = fmaf(a2.y, bv, c[ 9]);
        c[10] = fmaf(a2.z, bv, c[10]); c[11] = fmaf(a2.w, bv, c[11]);
        c[12] = fmaf(a3.x, bv, c[12]); c[13] = fmaf(a3.y, bv, c[13]);
        c[14] = fmaf(a3.z, bv, c[14]); c[15] = fmaf(a3.w, bv, c[15]);
    }
}

// Load 32x32 row-major matrix from global `src` and store TRANSPOSED into
// LDS dstT (row stride 36): dstT[k][i] = src[i][k].
__device__ __forceinline__ void load_transpose(const float* __restrict__ src,
                                               float* __restrict__ dstT, int lane)
{
    const float4* s4 = (const float4*)src;
    float4 v0 = s4[lane * 4 + 0], v1 = s4[lane * 4 + 1];
    float4 v2 = s4[lane * 4 + 2], v3 = s4[lane * 4 + 3];
    const int ro = lane >> 1;           // source row
    const int k0 = (lane & 1) * 16;     // source col base
    dstT[(k0 +  0) * 36 + ro] = v0.x; dstT[(k0 +  1) * 36 + ro] = v0.y;
    dstT[(k0 +  2) * 36 + ro] = v0.z; dstT[(k0 +  3) * 36 + ro] = v0.w;
    dstT[(k0 +  4) * 36 + ro] = v1.x; dstT[(k0 +  5) * 36 + ro] = v1.y;
    dstT[(k0 +  6) * 36 + ro] = v1.z; dstT[(k0 +  7) * 36 + ro] = v1.w;
    dstT[(k0 +  8) * 36 + ro] = v2.x; dstT[(k0 +  9) * 36 + ro] = v2.y;
    dstT[(k0 + 10) * 36 + ro] = v2.z; dstT[(k0 + 11) * 36 + ro] = v2.w;
    dstT[(k0 + 12) * 36 + ro] = v3.x; dstT[(k0 + 13) * 36 + ro] = v3.y;
    dstT[(k0 + 14) * 36 + ro] = v3.z; dstT[(k0 + 15) * 36 + ro] = v3.w;
}

__device__ __forceinline__ void load_straight(const float* __restrict__ src,
                                              float* __restrict__ dst, int lane)
{
    const float4* s4 = (const float4*)src;
    float4* d4 = (float4*)dst;
    d4[lane * 4 + 0] = s4[lane * 4 + 0];
    d4[lane * 4 + 1] = s4[lane * 4 + 1];
    d4[lane * 4 + 2] = s4[lane * 4 + 2];
    d4[lane * 4 + 3] = s4[lane * 4 + 3];
}

// One block (one wave) per quad index m: Q = ((Ma@Mb)@(Mc@Md)), scale by
// 2^-k so max column abs-sum lands in [1,2), store permuted + k.
__global__ __launch_bounds__(64) void tt_quad_kernel(const float* __restrict__ core)
{
    __shared__ float AT [32 * 36];
    __shared__ float Bb [32 * 32];
    __shared__ float A2T[32 * 36];
    __shared__ float B2 [32 * 32];

    const int m    = blockIdx.x;
    const int lane = threadIdx.x;
    const int h    = lane >> 5;
    const int j    = lane & 31;

    const int ia = (m >> 6) & 3;
    const int ib = (m >> 4) & 3;
    const int ic = (m >> 2) & 3;
    const int id =  m       & 3;

    float c[16];

    // stage 1: A2 = Ma @ Mb  (stored transposed)
    load_transpose(core + ia * 1024, AT, lane);
    load_straight (core + ib * 1024, Bb, lane);
    __syncthreads();
    mm32(AT, Bb, h, j, c);
    __syncthreads();
    {
        float4* dst = (float4*)(A2T + j * 36 + 16 * h);
        dst[0] = make_float4(c[ 0], c[ 1], c[ 2], c[ 3]);
        dst[1] = make_float4(c[ 4], c[ 5], c[ 6], c[ 7]);
        dst[2] = make_float4(c[ 8], c[ 9], c[10], c[11]);
        dst[3] = make_float4(c[12], c[13], c[14], c[15]);
    }
    __syncthreads();

    // stage 2: B2 = Mc @ Md  (stored normal)
    load_transpose(core + ic * 1024, AT, lane);
    load_straight (core + id * 1024, Bb, lane);
    __syncthreads();
    mm32(AT, Bb, h, j, c);
    __syncthreads();
#pragma unroll
    for (int r = 0; r < 16; ++r) B2[(16 * h + r) * 32 + j] = c[r];
    __syncthreads();

    // stage 3: Q = A2 @ B2
    mm32(A2T, B2, h, j, c);

    // normalize: k = floor(log2(max_j sum_i |Q[i][j]|)), Q *= 2^-k (exact)
    float ssum = 0.f;
#pragma unroll
    for (int r = 0; r < 16; ++r) ssum += fabsf(c[r]);
    ssum += __shfl_xor(ssum, 32);
    float cm = ssum;
    cm = fmaxf(cm, __shfl_xor(cm,  1));
    cm = fmaxf(cm, __shfl_xor(cm,  2));
    cm = fmaxf(cm, __shfl_xor(cm,  4));
    cm = fmaxf(cm, __shfl_xor(cm,  8));
    cm = fmaxf(cm, __shfl_xor(cm, 16));
    const int eb = __float_as_int(cm) & 0x7f800000;
    const float s = __int_as_float(0x7F000000 - eb);   // 2^-(E-127)
#pragma unroll
    for (int r = 0; r < 16; ++r) c[r] *= s;
    if (lane == 0) g_kQ[m] = (eb >> 23) - 127;

    float4* st = (float4*)(g_QTP + m * 1024);
    st[0 * 64 + lane] = make_float4(c[ 0], c[ 1], c[ 2], c[ 3]);
    st[1 * 64 + lane] = make_float4(c[ 4], c[ 5], c[ 6], c[ 7]);
    st[2 * 64 + lane] = make_float4(c[ 8], c[ 9], c[10], c[11]);
    st[3 * 64 + lane] = make_float4(c[12], c[13], c[14], c[15]);
}

// One step: prefetch quad TPF into (QL0..3), matvec u <- u @ Q using (QA0..3).
#define TTSTEP(QA0, QA1, QA2, QA3, TPF, QL0, QL1, QL2, QL3) do {              \
    const int mnext = idxs[(TPF)];                                            \
    const float4* pl = (const float4*)(qbytes + (mnext << 12) + laneoff16);   \
    QL0 = pl[0]; QL1 = pl[64]; QL2 = pl[128]; QL3 = pl[192];                  \
    const int ub = __float_as_int(u);                                         \
    float b0, b1, b2, b3, s0, s1, s2, s3;                                     \
    b0 = __int_as_float(__builtin_amdgcn_ds_bpermute(addrs[ 0], ub));         \
    b1 = __int_as_float(__builtin_amdgcn_ds_bpermute(addrs[ 1], ub));         \
    b2 = __int_as_float(__builtin_amdgcn_ds_bpermute(addrs[ 2], ub));         \
    b3 = __int_as_float(__builtin_amdgcn_ds_bpermute(addrs[ 3], ub));         \
    s0 = b0 * QA0.x; s1 = b1 * QA0.y; s2 = b2 * QA0.z; s3 = b3 * QA0.w;       \
    b0 = __int_as_float(__builtin_amdgcn_ds_bpermute(addrs[ 4], ub));         \
    b1 = __int_as_float(__builtin_amdgcn_ds_bpermute(addrs[ 5], ub));         \
    b2 = __int_as_float(__builtin_amdgcn_ds_bpermute(addrs[ 6], ub));         \
    b3 = __int_as_float(__builtin_amdgcn_ds_bpermute(addrs[ 7], ub));         \
    s0 = fmaf(b0, QA1.x, s0); s1 = fmaf(b1, QA1.y, s1);                       \
    s2 = fmaf(b2, QA1.z, s2); s3 = fmaf(b3, QA1.w, s3);                       \
    b0 = __int_as_float(__builtin_amdgcn_ds_bpermute(addrs[ 8], ub));         \
    b1 = __int_as_float(__builtin_amdgcn_ds_bpermute(addrs[ 9], ub));         \
    b2 = __int_as_float(__builtin_amdgcn_ds_bpermute(addrs[10], ub));         \
    b3 = __int_as_float(__builtin_amdgcn_ds_bpermute(addrs[11], ub));         \
    s0 = fmaf(b0, QA2.x, s0); s1 = fmaf(b1, QA2.y, s1);                       \
    s2 = fmaf(b2, QA2.z, s2); s3 = fmaf(b3, QA2.w, s3);                       \
    b0 = __int_as_float(__builtin_amdgcn_ds_bpermute(addrs[12], ub));         \
    b1 = __int_as_float(__builtin_amdgcn_ds_bpermute(addrs[13], ub));         \
    b2 = __int_as_float(__builtin_amdgcn_ds_bpermute(addrs[14], ub));         \
    b3 = __int_as_float(__builtin_amdgcn_ds_bpermute(addrs[15], ub));         \
    s0 = fmaf(b0, QA3.x, s0); s1 = fmaf(b1, QA3.y, s1);                       \
    s2 = fmaf(b2, QA3.z, s2); s3 = fmaf(b3, QA3.w, s3);                       \
    float pr = (s0 + s1) + (s2 + s3);                                         \
    pr += __shfl_xor(pr, 32);                                                 \
    u = pr;                                                                   \
} while (0)

// One block (one wave) per sequence; 256 quad steps.
__global__ __launch_bounds__(64) void tt_main_kernel(const int* __restrict__ X,
                                                     const float* __restrict__ Lb,
                                                     const float* __restrict__ Rb,
                                                     float* __restrict__ out)
{
    __shared__ int idxs[260];
    const int b    = blockIdx.x;
    const int lane = threadIdx.x;

    // quad indices + per-sequence sum of table exponents
    int ksum = 0;
    {
        const int4* Xq = (const int4*)(X + (size_t)b * TT_T);
#pragma unroll
        for (int it = 0; it < 4; ++it) {
            const int q = it * 64 + lane;
            const int4 xv = Xq[q];
            const int m = ((xv.x * 4 + xv.y) * 4 + xv.z) * 4 + xv.w;
            idxs[q] = m;
            ksum += g_kQ[m];
        }
        if (lane < 4) idxs[256 + lane] = 0;
    }
    __syncthreads();

    int addrs[16];
#pragma unroll
    for (int i = 0; i < 16; ++i) addrs[i] = ((lane >> 5) * 16 + i) * 4;

    float u = Lb[lane & 31];        // u[j], duplicated across halves
    int Ecorr = 0;
    int eb_pend = 0x3F800000;       // pending correction scale = 1.0

    const char* qbytes  = (const char*)g_QTP;
    const int laneoff16 = lane * 16;

    float4 Q00, Q01, Q02, Q03, Q10, Q11, Q12, Q13;
    float4 Q20, Q21, Q22, Q23, Q30, Q31, Q32, Q33;
    {
        int m0 = idxs[0];
        const float4* p = (const float4*)(qbytes + (m0 << 12) + laneoff16);
        Q00 = p[0]; Q01 = p[64]; Q02 = p[128]; Q03 = p[192];
        int m1 = idxs[1];
        p = (const float4*)(qbytes + (m1 << 12) + laneoff16);
        Q10 = p[0]; Q11 = p[64]; Q12 = p[128]; Q13 = p[192];
        int m2 = idxs[2];
        p = (const float4*)(qbytes + (m2 << 12) + laneoff16);
        Q20 = p[0]; Q21 = p[64]; Q22 = p[128]; Q23 = p[192];
    }

#pragma unroll 1
    for (int I = 0; I < 64; ++I) {
        const int t0 = I * 4;
        TTSTEP(Q00, Q01, Q02, Q03, t0 + 3, Q30, Q31, Q32, Q33);
        TTSTEP(Q10, Q11, Q12, Q13, t0 + 4, Q00, Q01, Q02, Q03);
        TTSTEP(Q20, Q21, Q22, Q23, t0 + 5, Q10, Q11, Q12, Q13);
        TTSTEP(Q30, Q31, Q32, Q33, t0 + 6, Q20, Q21, Q22, Q23);

        // deferred drift correction: measure max|u| now, apply PREVIOUS
        // iteration's scale immediately (keeps the 5-level shuffle chain
        // off the critical path). All scales are exact powers of two.
        float za = fabsf(u);
        za = fmaxf(za, __shfl_xor(za,  1));
        za = fmaxf(za, __shfl_xor(za,  2));
        za = fmaxf(za, __shfl_xor(za,  4));
        za = fmaxf(za, __shfl_xor(za,  8));
        za = fmaxf(za, __shfl_xor(za, 16));
        u *= __int_as_float(0x7F000000 - eb_pend);      // apply pending
        Ecorr += (eb_pend >> 23);
        // next scale: exponent of (za * applied_scale)
        eb_pend = (__float_as_int(za) & 0x7f800000) - eb_pend + 0x3F800000;
    }

    // epilogue: dot with right boundary, assemble logprob
    float p = u * Rb[lane & 31];
    p += __shfl_xor(p,  1);
    p += __shfl_xor(p,  2);
    p += __shfl_xor(p,  4);
    p += __shfl_xor(p,  8);
    p += __shfl_xor(p, 16);

    ksum += __shfl_xor(ksum,  1);
    ksum += __shfl_xor(ksum,  2);
    ksum += __shfl_xor(ksum,  4);
    ksum += __shfl_xor(ksum,  8);
    ksum += __shfl_xor(ksum, 16);
    ksum += __shfl_xor(ksum, 32);

    if (lane == 0) {
        const float S = (float)(Ecorr - 127 * 64 + ksum);
        out[b] = 2.0f * (S * 0.6931471805599453f + logf(fabsf(p)));
    }
}

extern "C" void kernel_launch(void* const* d_in, const int* in_sizes, int n_in,
                              void* d_out, int out_size, void* d_ws, size_t ws_size,
                              hipStream_t stream)
{
    const int*   X    = (const int*)d_in[0];
    const float* core = (const float*)d_in[1];
    const float* Lb   = (const float*)d_in[2];
    const float* Rb   = (const float*)d_in[3];
    float* out = (float*)d_out;

    tt_quad_kernel<<<dim3(256), dim3(64), 0, stream>>>(core);
    tt_main_kernel<<<dim3(256), dim3(64), 0, stream>>>(X, Lb, Rb, out);
}

// Round 4
// 84.705 us; speedup vs baseline: 1.3893x; 1.3893x over previous
//
#include <hip/hip_runtime.h>
#include <math.h>

// Tensor-train log-likelihood, B=256, T=1024, d=4, D=32.
// Radix-4: precompute all 4^4 = 256 quad matrix products (pre-scaled by
// exact powers of two), then 256 chain steps per sequence, one wave/sequence.
// Round 4:
//  - column-per-lane matvec: lane j holds Q column j (8 float4); u[i]
//    broadcast via v_readlane -> SGPR; FMA result IS next u (no DS ops).
//  - asm global_load prefetch depth 3 + counted s_waitcnt vmcnt(24).
//  - s_waitcnt vmcnt(0) after the loop: in-flight asm loads at s_endpgm
//    corrupt successor waves' VGPRs (round-3 failure root cause).
//  - drift rescale cadence 4, deferred 1 iter (round-2-proven envelope).

#define TT_B 256
#define TT_T 1024

// Quad table, column-major per quad: QT[m][j][i] = Qs_m[i][j]  (4KB/quad).
// Qs_m = Q_m * 2^-kQ[m], kQ exact (power-of-2 scaling).
__device__ float g_QTP[256 * 1024];
__device__ int   g_kQ[256];

// C[i][j] for i = 16h+r (r=0..15): c[r] = sum_k AT[k][16h+r] * B[k][j]
__device__ __forceinline__ void mm32(const float* __restrict__ AT,
                                     const float* __restrict__ B,
                                     int h, int j, float c[16])
{
#pragma unroll
    for (int r = 0; r < 16; ++r) c[r] = 0.f;
#pragma unroll 4
    for (int k = 0; k < 32; ++k) {
        float bv = B[k * 32 + j];
        const float4* ar = (const float4*)(AT + k * 36 + 16 * h);
        float4 a0 = ar[0], a1 = ar[1], a2 = ar[2], a3 = ar[3];
        c[ 0] = fmaf(a0.x, bv, c[ 0]); c[ 1] = fmaf(a0.y, bv, c[ 1]);
        c[ 2] = fmaf(a0.z, bv, c[ 2]); c[ 3] = fmaf(a0.w, bv, c[ 3]);
        c[ 4] = fmaf(a1.x, bv, c[ 4]); c[ 5] = fmaf(a1.y, bv, c[ 5]);
        c[ 6] = fmaf(a1.z, bv, c[ 6]); c[ 7] = fmaf(a1.w, bv, c[ 7]);
        c[ 8] = fmaf(a2.x, bv, c[ 8]); c[ 9] = fmaf(a2.y, bv, c[ 9]);
        c[10] = fmaf(a2.z, bv, c[10]); c[11] = fmaf(a2.w, bv, c[11]);
        c[12] = fmaf(a3.x, bv, c[12]); c[13] = fmaf(a3.y, bv, c[13]);
        c[14] = fmaf(a3.z, bv, c[14]); c[15] = fmaf(a3.w, bv, c[15]);
    }
}

__device__ __forceinline__ void load_transpose(const float* __restrict__ src,
                                               float* __restrict__ dstT, int lane)
{
    const float4* s4 = (const float4*)src;
    float4 v0 = s4[lane * 4 + 0], v1 = s4[lane * 4 + 1];
    float4 v2 = s4[lane * 4 + 2], v3 = s4[lane * 4 + 3];
    const int ro = lane >> 1;
    const int k0 = (lane & 1) * 16;
    dstT[(k0 +  0) * 36 + ro] = v0.x; dstT[(k0 +  1) * 36 + ro] = v0.y;
    dstT[(k0 +  2) * 36 + ro] = v0.z; dstT[(k0 +  3) * 36 + ro] = v0.w;
    dstT[(k0 +  4) * 36 + ro] = v1.x; dstT[(k0 +  5) * 36 + ro] = v1.y;
    dstT[(k0 +  6) * 36 + ro] = v1.z; dstT[(k0 +  7) * 36 + ro] = v1.w;
    dstT[(k0 +  8) * 36 + ro] = v2.x; dstT[(k0 +  9) * 36 + ro] = v2.y;
    dstT[(k0 + 10) * 36 + ro] = v2.z; dstT[(k0 + 11) * 36 + ro] = v2.w;
    dstT[(k0 + 12) * 36 + ro] = v3.x; dstT[(k0 + 13) * 36 + ro] = v3.y;
    dstT[(k0 + 14) * 36 + ro] = v3.z; dstT[(k0 + 15) * 36 + ro] = v3.w;
}

__device__ __forceinline__ void load_straight(const float* __restrict__ src,
                                              float* __restrict__ dst, int lane)
{
    const float4* s4 = (const float4*)src;
    float4* d4 = (float4*)dst;
    d4[lane * 4 + 0] = s4[lane * 4 + 0];
    d4[lane * 4 + 1] = s4[lane * 4 + 1];
    d4[lane * 4 + 2] = s4[lane * 4 + 2];
    d4[lane * 4 + 3] = s4[lane * 4 + 3];
}

__global__ __launch_bounds__(64) void tt_quad_kernel(const float* __restrict__ core)
{
    __shared__ float AT [32 * 36];
    __shared__ float Bb [32 * 32];
    __shared__ float A2T[32 * 36];
    __shared__ float B2 [32 * 32];

    const int m    = blockIdx.x;
    const int lane = threadIdx.x;
    const int h    = lane >> 5;
    const int j    = lane & 31;

    const int ia = (m >> 6) & 3;
    const int ib = (m >> 4) & 3;
    const int ic = (m >> 2) & 3;
    const int id =  m       & 3;

    float c[16];

    load_transpose(core + ia * 1024, AT, lane);
    load_straight (core + ib * 1024, Bb, lane);
    __syncthreads();
    mm32(AT, Bb, h, j, c);
    __syncthreads();
    {
        float4* dst = (float4*)(A2T + j * 36 + 16 * h);
        dst[0] = make_float4(c[ 0], c[ 1], c[ 2], c[ 3]);
        dst[1] = make_float4(c[ 4], c[ 5], c[ 6], c[ 7]);
        dst[2] = make_float4(c[ 8], c[ 9], c[10], c[11]);
        dst[3] = make_float4(c[12], c[13], c[14], c[15]);
    }
    __syncthreads();

    load_transpose(core + ic * 1024, AT, lane);
    load_straight (core + id * 1024, Bb, lane);
    __syncthreads();
    mm32(AT, Bb, h, j, c);
    __syncthreads();
#pragma unroll
    for (int r = 0; r < 16; ++r) B2[(16 * h + r) * 32 + j] = c[r];
    __syncthreads();

    mm32(A2T, B2, h, j, c);

    // normalize: k = floor(log2(max_j sum_i |Q[i][j]|)), Q *= 2^-k (exact)
    float ssum = 0.f;
#pragma unroll
    for (int r = 0; r < 16; ++r) ssum += fabsf(c[r]);
    ssum += __shfl_xor(ssum, 32);
    float cm = ssum;
    cm = fmaxf(cm, __shfl_xor(cm,  1));
    cm = fmaxf(cm, __shfl_xor(cm,  2));
    cm = fmaxf(cm, __shfl_xor(cm,  4));
    cm = fmaxf(cm, __shfl_xor(cm,  8));
    cm = fmaxf(cm, __shfl_xor(cm, 16));
    const int eb = __float_as_int(cm) & 0x7f800000;
    const float s = __int_as_float(0x7F000000 - eb);   // 2^-(E-127), exact
#pragma unroll
    for (int r = 0; r < 16; ++r) c[r] *= s;
    if (lane == 0) g_kQ[m] = (eb >> 23) - 127;

    // store TRANSPOSED: QT[m][j][i] = Qs[i][j]; lane (h,j) holds rows 16h+r
    // of column j -> 16 consecutive floats at j*32 + 16h.
    float4* st = (float4*)(g_QTP + m * 1024 + j * 32 + h * 16);
    st[0] = make_float4(c[ 0], c[ 1], c[ 2], c[ 3]);
    st[1] = make_float4(c[ 4], c[ 5], c[ 6], c[ 7]);
    st[2] = make_float4(c[ 8], c[ 9], c[10], c[11]);
    st[3] = make_float4(c[12], c[13], c[14], c[15]);
}

// ---- main chain kernel ----------------------------------------------------

// Issue 8 asm loads (one 4KB column-slab, dup across halves) for quad MU.
#define LOAD8(L0, L1, L2, L3, L4, L5, L6, L7, MU) do {                        \
    const int voff_ = (((MU) << 12) | laneoff);                               \
    asm volatile("global_load_dwordx4 %0, %1, %2"            : "=v"(L0) : "v"(voff_), "s"(qtb)); \
    asm volatile("global_load_dwordx4 %0, %1, %2 offset:16"  : "=v"(L1) : "v"(voff_), "s"(qtb)); \
    asm volatile("global_load_dwordx4 %0, %1, %2 offset:32"  : "=v"(L2) : "v"(voff_), "s"(qtb)); \
    asm volatile("global_load_dwordx4 %0, %1, %2 offset:48"  : "=v"(L3) : "v"(voff_), "s"(qtb)); \
    asm volatile("global_load_dwordx4 %0, %1, %2 offset:64"  : "=v"(L4) : "v"(voff_), "s"(qtb)); \
    asm volatile("global_load_dwordx4 %0, %1, %2 offset:80"  : "=v"(L5) : "v"(voff_), "s"(qtb)); \
    asm volatile("global_load_dwordx4 %0, %1, %2 offset:96"  : "=v"(L6) : "v"(voff_), "s"(qtb)); \
    asm volatile("global_load_dwordx4 %0, %1, %2 offset:112" : "=v"(L7) : "v"(voff_), "s"(qtb)); \
} while (0)

#define RLANE(i) __int_as_float(__builtin_amdgcn_readlane(ub_, (i)))

// One step: prefetch bank L (quad MU), refill index reg ML=idxs[TI],
// broadcast u via readlane, wait for bank U (24 = 3 banks x 8 loads remain
// outstanding), matvec u[j] <- sum_i u[i] * Q[i][j].
#define TTSTEP(U0,U1,U2,U3,U4,U5,U6,U7, L0,L1,L2,L3,L4,L5,L6,L7, MU, ML, TI) do { \
    LOAD8(L0, L1, L2, L3, L4, L5, L6, L7, MU);                                \
    ML = idxs[(TI)];                                                          \
    const int ub_ = __float_as_int(u);                                        \
    const float w00 = RLANE( 0), w01 = RLANE( 1), w02 = RLANE( 2), w03 = RLANE( 3); \
    const float w04 = RLANE( 4), w05 = RLANE( 5), w06 = RLANE( 6), w07 = RLANE( 7); \
    const float w08 = RLANE( 8), w09 = RLANE( 9), w10 = RLANE(10), w11 = RLANE(11); \
    const float w12 = RLANE(12), w13 = RLANE(13), w14 = RLANE(14), w15 = RLANE(15); \
    const float w16 = RLANE(16), w17 = RLANE(17), w18 = RLANE(18), w19 = RLANE(19); \
    const float w20 = RLANE(20), w21 = RLANE(21), w22 = RLANE(22), w23 = RLANE(23); \
    const float w24 = RLANE(24), w25 = RLANE(25), w26 = RLANE(26), w27 = RLANE(27); \
    const float w28 = RLANE(28), w29 = RLANE(29), w30 = RLANE(30), w31 = RLANE(31); \
    asm volatile("s_waitcnt vmcnt(24)" ::: "memory");                         \
    __builtin_amdgcn_sched_barrier(0);                                        \
    float a0_ = w00 * U0.x, a1_ = w01 * U0.y, a2_ = w02 * U0.z, a3_ = w03 * U0.w; \
    a0_ = fmaf(w04, U1.x, a0_); a1_ = fmaf(w05, U1.y, a1_);                   \
    a2_ = fmaf(w06, U1.z, a2_); a3_ = fmaf(w07, U1.w, a3_);                   \
    a0_ = fmaf(w08, U2.x, a0_); a1_ = fmaf(w09, U2.y, a1_);                   \
    a2_ = fmaf(w10, U2.z, a2_); a3_ = fmaf(w11, U2.w, a3_);                   \
    a0_ = fmaf(w12, U3.x, a0_); a1_ = fmaf(w13, U3.y, a1_);                   \
    a2_ = fmaf(w14, U3.z, a2_); a3_ = fmaf(w15, U3.w, a3_);                   \
    a0_ = fmaf(w16, U4.x, a0_); a1_ = fmaf(w17, U4.y, a1_);                   \
    a2_ = fmaf(w18, U4.z, a2_); a3_ = fmaf(w19, U4.w, a3_);                   \
    a0_ = fmaf(w20, U5.x, a0_); a1_ = fmaf(w21, U5.y, a1_);                   \
    a2_ = fmaf(w22, U5.z, a2_); a3_ = fmaf(w23, U5.w, a3_);                   \
    a0_ = fmaf(w24, U6.x, a0_); a1_ = fmaf(w25, U6.y, a1_);                   \
    a2_ = fmaf(w26, U6.z, a2_); a3_ = fmaf(w27, U6.w, a3_);                   \
    a0_ = fmaf(w28, U7.x, a0_); a1_ = fmaf(w29, U7.y, a1_);                   \
    a2_ = fmaf(w30, U7.z, a2_); a3_ = fmaf(w31, U7.w, a3_);                   \
    u = (a0_ + a1_) + (a2_ + a3_);                                            \
} while (0)

__global__ __launch_bounds__(64, 1) void tt_main_kernel(const int* __restrict__ X,
                                                        const float* __restrict__ Lb,
                                                        const float* __restrict__ Rb,
                                                        float* __restrict__ out)
{
    __shared__ int idxs[272];
    const int b    = blockIdx.x;
    const int lane = threadIdx.x;

    int ksum = 0;
    {
        const int4* Xq = (const int4*)(X + (size_t)b * TT_T);
#pragma unroll
        for (int it = 0; it < 4; ++it) {
            const int q = it * 64 + lane;
            const int4 xv = Xq[q];
            const int m = ((xv.x * 4 + xv.y) * 4 + xv.z) * 4 + xv.w;
            idxs[q] = m;
            ksum += g_kQ[m];
        }
        if (lane < 16) idxs[256 + lane] = 0;
    }
    __syncthreads();

    const int laneoff = (lane & 31) * 128;     // byte offset of column (lane&31)
    const float* qtb = g_QTP;

    float4 A0, A1, A2, A3, A4, A5, A6, A7;
    float4 B0, B1, B2, B3, B4, B5, B6, B7;
    float4 C0, C1, C2, C3, C4, C5, C6, C7;
    float4 D0, D1, D2, D3, D4, D5, D6, D7;

    // prime banks for steps 0,1,2 (24 loads outstanding) + index pipeline
    LOAD8(A0, A1, A2, A3, A4, A5, A6, A7, idxs[0]);
    LOAD8(B0, B1, B2, B3, B4, B5, B6, B7, idxs[1]);
    LOAD8(C0, C1, C2, C3, C4, C5, C6, C7, idxs[2]);
    int mA = idxs[3], mB = idxs[4], mC = 0, mD = 0;

    float u = Lb[lane & 31];        // u[j] on lane j (dup across halves)
    int Ecorr = 0;
    int eb_pend = 0x3F800000;       // pending correction scale = 1.0

#pragma unroll 1
    for (int I = 0; I < 64; ++I) {
        const int t0 = I * 4;
        TTSTEP(A0,A1,A2,A3,A4,A5,A6,A7, D0,D1,D2,D3,D4,D5,D6,D7, mA, mC, t0 + 5);
        TTSTEP(B0,B1,B2,B3,B4,B5,B6,B7, A0,A1,A2,A3,A4,A5,A6,A7, mB, mD, t0 + 6);
        TTSTEP(C0,C1,C2,C3,C4,C5,C6,C7, B0,B1,B2,B3,B4,B5,B6,B7, mC, mA, t0 + 7);
        TTSTEP(D0,D1,D2,D3,D4,D5,D6,D7, C0,C1,C2,C3,C4,C5,C6,C7, mD, mB, t0 + 8);

        // deferred drift correction every 4 steps (round-2-proven envelope):
        // measure max|u| now, apply PREVIOUS iteration's scale (all scales
        // exact powers of two; only exponent bookkeeping).
        float za = fabsf(u);
        za = fmaxf(za, __shfl_xor(za,  1));
        za = fmaxf(za, __shfl_xor(za,  2));
        za = fmaxf(za, __shfl_xor(za,  4));
        za = fmaxf(za, __shfl_xor(za,  8));
        za = fmaxf(za, __shfl_xor(za, 16));
        u *= __int_as_float(0x7F000000 - eb_pend);      // apply pending
        Ecorr += (eb_pend >> 23);
        eb_pend = (__float_as_int(za) & 0x7f800000) - eb_pend + 0x3F800000;
    }

    // Drain our asm loads: in-flight loads at s_endpgm would corrupt VGPRs
    // of waves that reuse this slot (round-3 failure root cause).
    asm volatile("s_waitcnt vmcnt(0)" ::: "memory");

    // epilogue: dot with right boundary, assemble logprob
    float p = u * Rb[lane & 31];
    p += __shfl_xor(p,  1);
    p += __shfl_xor(p,  2);
    p += __shfl_xor(p,  4);
    p += __shfl_xor(p,  8);
    p += __shfl_xor(p, 16);

    ksum += __shfl_xor(ksum,  1);
    ksum += __shfl_xor(ksum,  2);
    ksum += __shfl_xor(ksum,  4);
    ksum += __shfl_xor(ksum,  8);
    ksum += __shfl_xor(ksum, 16);
    ksum += __shfl_xor(ksum, 32);

    if (lane == 0) {
        const float S = (float)(Ecorr - 127 * 64 + ksum);
        out[b] = 2.0f * (S * 0.6931471805599453f + logf(fabsf(p)));
    }
}

extern "C" void kernel_launch(void* const* d_in, const int* in_sizes, int n_in,
                              void* d_out, int out_size, void* d_ws, size_t ws_size,
                              hipStream_t stream)
{
    const int*   X    = (const int*)d_in[0];
    const float* core = (const float*)d_in[1];
    const float* Lb   = (const float*)d_in[2];
    const float* Rb   = (const float*)d_in[3];
    float* out = (float*)d_out;

    tt_quad_kernel<<<dim3(256), dim3(64), 0, stream>>>(core);
    tt_main_kernel<<<dim3(256), dim3(64), 0, stream>>>(X, Lb, Rb, out);
}

// Round 8
// 33.824 us; speedup vs baseline: 3.4792x; 2.5043x over previous
//
#include <hip/hip_runtime.h>
#include <math.h>

// Tensor-train log-likelihood, B=256, T=1024, d=4, D=32.
// Round 8 (= round 7 + compile fix): radix-4 quad table as bf16 MFMA
// B-fragments (fwd: Q, bwd: Q^T) in ONE merged table (SGPR base; direction
// folded into the VGPR offset — round-7 compile error was a per-thread
// ternary base pointer landing in VGPRs, invalid for global_load saddr).
// Bidirectional chain split (2 waves/seq x 128 steps), matvec via
// mfma_f32_16x16x32_bf16 with u replicated across A-rows (slot-permutation
// cancellation: A and B fragments are filled through the same assumed
// k(l,s) mapping and the same pkbf16 pairing, so any hardware slot
// permutation cancels; only the m89-verified C/D col mapping matters).
// 2 asm dwordx4 loads/step, 4 banks, counted vmcnt(6), vmcnt(0) drain
// before s_endpgm (round-3 lesson).

#define TT_B 256
#define TT_T 1024

typedef __attribute__((ext_vector_type(8))) short bf16x8;
typedef __attribute__((ext_vector_type(4))) float f32x4;

// Merged fragment table: [dir][m][H][lane] = uint4 (8 bf16, slots paired
// (2s,2s+1)). dir 0 = fwd (Q), dir 1 = bwd (Q^T). 2KB per quad per dir;
// dir stride = 256*2*64*16B = 512KB = 1<<19.
__device__ uint4 g_QT[2 * 256 * 2 * 64];
__device__ int   g_kQ[256];

__device__ __forceinline__ unsigned pkbf16(float lo, float hi)
{
    unsigned r;
    asm volatile("v_cvt_pk_bf16_f32 %0, %1, %2" : "=v"(r) : "v"(lo), "v"(hi));
    return r;
}

__device__ __forceinline__ bf16x8 as_bf16x8(int4 v)
{
    union { int4 i; bf16x8 h; } u; u.i = v; return u.h;
}

// ---- quad-product precompute ----------------------------------------------

__device__ __forceinline__ void mm32(const float* __restrict__ AT,
                                     const float* __restrict__ B,
                                     int h, int j, float c[16])
{
#pragma unroll
    for (int r = 0; r < 16; ++r) c[r] = 0.f;
#pragma unroll 4
    for (int k = 0; k < 32; ++k) {
        float bv = B[k * 32 + j];
        const float4* ar = (const float4*)(AT + k * 36 + 16 * h);
        float4 a0 = ar[0], a1 = ar[1], a2 = ar[2], a3 = ar[3];
        c[ 0] = fmaf(a0.x, bv, c[ 0]); c[ 1] = fmaf(a0.y, bv, c[ 1]);
        c[ 2] = fmaf(a0.z, bv, c[ 2]); c[ 3] = fmaf(a0.w, bv, c[ 3]);
        c[ 4] = fmaf(a1.x, bv, c[ 4]); c[ 5] = fmaf(a1.y, bv, c[ 5]);
        c[ 6] = fmaf(a1.z, bv, c[ 6]); c[ 7] = fmaf(a1.w, bv, c[ 7]);
        c[ 8] = fmaf(a2.x, bv, c[ 8]); c[ 9] = fmaf(a2.y, bv, c[ 9]);
        c[10] = fmaf(a2.z, bv, c[10]); c[11] = fmaf(a2.w, bv, c[11]);
        c[12] = fmaf(a3.x, bv, c[12]); c[13] = fmaf(a3.y, bv, c[13]);
        c[14] = fmaf(a3.z, bv, c[14]); c[15] = fmaf(a3.w, bv, c[15]);
    }
}

__device__ __forceinline__ void load_transpose(const float* __restrict__ src,
                                               float* __restrict__ dstT, int lane)
{
    const float4* s4 = (const float4*)src;
    float4 v0 = s4[lane * 4 + 0], v1 = s4[lane * 4 + 1];
    float4 v2 = s4[lane * 4 + 2], v3 = s4[lane * 4 + 3];
    const int ro = lane >> 1;
    const int k0 = (lane & 1) * 16;
    dstT[(k0 +  0) * 36 + ro] = v0.x; dstT[(k0 +  1) * 36 + ro] = v0.y;
    dstT[(k0 +  2) * 36 + ro] = v0.z; dstT[(k0 +  3) * 36 + ro] = v0.w;
    dstT[(k0 +  4) * 36 + ro] = v1.x; dstT[(k0 +  5) * 36 + ro] = v1.y;
    dstT[(k0 +  6) * 36 + ro] = v1.z; dstT[(k0 +  7) * 36 + ro] = v1.w;
    dstT[(k0 +  8) * 36 + ro] = v2.x; dstT[(k0 +  9) * 36 + ro] = v2.y;
    dstT[(k0 + 10) * 36 + ro] = v2.z; dstT[(k0 + 11) * 36 + ro] = v2.w;
    dstT[(k0 + 12) * 36 + ro] = v3.x; dstT[(k0 + 13) * 36 + ro] = v3.y;
    dstT[(k0 + 14) * 36 + ro] = v3.z; dstT[(k0 + 15) * 36 + ro] = v3.w;
}

__device__ __forceinline__ void load_straight(const float* __restrict__ src,
                                              float* __restrict__ dst, int lane)
{
    const float4* s4 = (const float4*)src;
    float4* d4 = (float4*)dst;
    d4[lane * 4 + 0] = s4[lane * 4 + 0];
    d4[lane * 4 + 1] = s4[lane * 4 + 1];
    d4[lane * 4 + 2] = s4[lane * 4 + 2];
    d4[lane * 4 + 3] = s4[lane * 4 + 3];
}

__global__ __launch_bounds__(64) void tt_quad_kernel(const float* __restrict__ core)
{
    __shared__ float AT [32 * 36];
    __shared__ float Bb [32 * 32];
    __shared__ float A2T[32 * 36];
    __shared__ float B2 [32 * 32];
    __shared__ float Qs [32 * 33];

    const int m    = blockIdx.x;
    const int lane = threadIdx.x;
    const int h    = lane >> 5;
    const int j    = lane & 31;

    const int ia = (m >> 6) & 3;
    const int ib = (m >> 4) & 3;
    const int ic = (m >> 2) & 3;
    const int id =  m       & 3;

    float c[16];

    load_transpose(core + ia * 1024, AT, lane);
    load_straight (core + ib * 1024, Bb, lane);
    __syncthreads();
    mm32(AT, Bb, h, j, c);
    __syncthreads();
    {
        float4* dst = (float4*)(A2T + j * 36 + 16 * h);
        dst[0] = make_float4(c[ 0], c[ 1], c[ 2], c[ 3]);
        dst[1] = make_float4(c[ 4], c[ 5], c[ 6], c[ 7]);
        dst[2] = make_float4(c[ 8], c[ 9], c[10], c[11]);
        dst[3] = make_float4(c[12], c[13], c[14], c[15]);
    }
    __syncthreads();

    load_transpose(core + ic * 1024, AT, lane);
    load_straight (core + id * 1024, Bb, lane);
    __syncthreads();
    mm32(AT, Bb, h, j, c);
    __syncthreads();
#pragma unroll
    for (int r = 0; r < 16; ++r) B2[(16 * h + r) * 32 + j] = c[r];
    __syncthreads();

    mm32(A2T, B2, h, j, c);

    // normalize: k = floor(log2(max_j sum_i |Q[i][j]|)), Q *= 2^-k (exact)
    float ssum = 0.f;
#pragma unroll
    for (int r = 0; r < 16; ++r) ssum += fabsf(c[r]);
    ssum += __shfl_xor(ssum, 32);
    float cm = ssum;
    cm = fmaxf(cm, __shfl_xor(cm,  1));
    cm = fmaxf(cm, __shfl_xor(cm,  2));
    cm = fmaxf(cm, __shfl_xor(cm,  4));
    cm = fmaxf(cm, __shfl_xor(cm,  8));
    cm = fmaxf(cm, __shfl_xor(cm, 16));
    const int eb = __float_as_int(cm) & 0x7f800000;
    const float s = __int_as_float(0x7F000000 - eb);   // 2^-(E-127), exact
#pragma unroll
    for (int r = 0; r < 16; ++r) c[r] *= s;
    if (lane == 0) g_kQ[m] = (eb >> 23) - 127;

    // full scaled matrix to LDS, then emit bf16 B-fragments
#pragma unroll
    for (int r = 0; r < 16; ++r) Qs[(16 * h + r) * 33 + j] = c[r];
    __syncthreads();

    const int g  = lane >> 4;      // k-octet group
    const int jj = lane & 15;      // fragment column
#pragma unroll
    for (int H = 0; H < 2; ++H) {
        // fwd (dir 0): slot s = Qs[8g+s][16H+jj]
        uint4 wf;
        wf.x = pkbf16(Qs[(8*g+0)*33 + 16*H+jj], Qs[(8*g+1)*33 + 16*H+jj]);
        wf.y = pkbf16(Qs[(8*g+2)*33 + 16*H+jj], Qs[(8*g+3)*33 + 16*H+jj]);
        wf.z = pkbf16(Qs[(8*g+4)*33 + 16*H+jj], Qs[(8*g+5)*33 + 16*H+jj]);
        wf.w = pkbf16(Qs[(8*g+6)*33 + 16*H+jj], Qs[(8*g+7)*33 + 16*H+jj]);
        g_QT[(m * 2 + H) * 64 + lane] = wf;
        // bwd (dir 1, Q^T): slot s = Qs[16H+jj][8g+s]
        const float* rp = &Qs[(16*H + jj) * 33];
        uint4 wb;
        wb.x = pkbf16(rp[8*g+0], rp[8*g+1]);
        wb.y = pkbf16(rp[8*g+2], rp[8*g+3]);
        wb.z = pkbf16(rp[8*g+4], rp[8*g+5]);
        wb.w = pkbf16(rp[8*g+6], rp[8*g+7]);
        g_QT[32768 + (m * 2 + H) * 64 + lane] = wb;
    }
}

// ---- main chain kernel ----------------------------------------------------

// SGPR base (compile-time global) + per-lane VGPR offset incl. direction.
#define LOAD2(UB0, UB1, MIDX) do {                                            \
    const int voff_ = (tabof | ((MIDX) << 11) | (lane << 4));                 \
    asm volatile("global_load_dwordx4 %0, %1, %2"             : "=v"(UB0) : "v"(voff_), "s"(qtb)); \
    asm volatile("global_load_dwordx4 %0, %1, %2 offset:1024" : "=v"(UB1) : "v"(voff_), "s"(qtb)); \
} while (0)

// One step: gather u into A-octets (f32 bpermute, hi/lo via source-lane
// redirect), pack to bf16 pairs, wait this bank's 2 loads (6 = 3 banks
// outstanding), 2 MFMAs (cols 0-15 / 16-31), reload same bank for t+4.
#define TTSTEP(UB0, UB1, MIDX) do {                                           \
    const float srcv_ = hisel ? v_hi : v_lo;                                  \
    const int sb_ = __float_as_int(srcv_);                                    \
    const int r0_ = __builtin_amdgcn_ds_bpermute(a0 +  0, sb_);               \
    const int r1_ = __builtin_amdgcn_ds_bpermute(a0 +  4, sb_);               \
    const int r2_ = __builtin_amdgcn_ds_bpermute(a0 +  8, sb_);               \
    const int r3_ = __builtin_amdgcn_ds_bpermute(a0 + 12, sb_);               \
    const int r4_ = __builtin_amdgcn_ds_bpermute(a0 + 16, sb_);               \
    const int r5_ = __builtin_amdgcn_ds_bpermute(a0 + 20, sb_);               \
    const int r6_ = __builtin_amdgcn_ds_bpermute(a0 + 24, sb_);               \
    const int r7_ = __builtin_amdgcn_ds_bpermute(a0 + 28, sb_);               \
    int4 aw_;                                                                 \
    aw_.x = (int)pkbf16(__int_as_float(r0_), __int_as_float(r1_));            \
    aw_.y = (int)pkbf16(__int_as_float(r2_), __int_as_float(r3_));            \
    aw_.z = (int)pkbf16(__int_as_float(r4_), __int_as_float(r5_));            \
    aw_.w = (int)pkbf16(__int_as_float(r6_), __int_as_float(r7_));            \
    const bf16x8 af_ = as_bf16x8(aw_);                                        \
    const bf16x8 bf0_ = as_bf16x8(UB0);                                       \
    const bf16x8 bf1_ = as_bf16x8(UB1);                                       \
    asm volatile("s_waitcnt vmcnt(6)" ::: "memory");                          \
    __builtin_amdgcn_sched_barrier(0);                                        \
    const f32x4 d1_ = __builtin_amdgcn_mfma_f32_16x16x32_bf16(af_, bf0_, zero, 0, 0, 0); \
    const f32x4 d2_ = __builtin_amdgcn_mfma_f32_16x16x32_bf16(af_, bf1_, zero, 0, 0, 0); \
    LOAD2(UB0, UB1, (MIDX));                                                  \
    v_lo = d1_[0];                                                            \
    v_hi = d2_[0];                                                            \
} while (0)

__global__ __launch_bounds__(128, 1) void tt_main_kernel(const int* __restrict__ X,
                                                         const float* __restrict__ Lb,
                                                         const float* __restrict__ Rb,
                                                         float* __restrict__ out)
{
    __shared__ int   idxs[256];
    __shared__ float vbl[16], vbh[16];
    __shared__ int   kred[2];
    __shared__ int   ecred;

    const int b    = blockIdx.x;
    const int tid  = threadIdx.x;
    const int wid  = tid >> 6;        // 0 = forward, 1 = backward
    const int lane = tid & 63;

    // quad indices + table-exponent sum (the two waves cover all 256 entries)
    int ksum = 0;
    {
        const int4* Xq = (const int4*)(X + (size_t)b * TT_T);
#pragma unroll
        for (int it = 0; it < 2; ++it) {
            const int q = it * 128 + tid;
            const int4 xv = Xq[q];
            const int m = ((xv.x * 4 + xv.y) * 4 + xv.z) * 4 + xv.w;
            idxs[q] = m;
            ksum += g_kQ[m];
        }
    }
    ksum += __shfl_xor(ksum,  1);
    ksum += __shfl_xor(ksum,  2);
    ksum += __shfl_xor(ksum,  4);
    ksum += __shfl_xor(ksum,  8);
    ksum += __shfl_xor(ksum, 16);
    ksum += __shfl_xor(ksum, 32);
    if (lane == 0) kred[wid] = ksum;
    __syncthreads();

    const uint4* qtb  = g_QT;                 // compile-time global -> SGPR
    const int    tabof = wid << 19;           // direction in the VGPR offset
    const float* vsrc = wid ? Rb : Lb;
    const int jj = lane & 15;
    float v_lo = vsrc[jj];            // v[jj]      (replicated across groups)
    float v_hi = vsrc[16 + jj];       // v[16+jj]
    const bool hisel = ((lane & 48) == 16);            // source lanes 16-31 carry v_hi
    const int  a0    = ((lane >> 4) & 1) * 32 + ((lane >> 5) & 1) * 64;

    int   Ecorr = 0;
    float za_p = 1.f, m1_p = 1.f, m2_p = 1.f, m3_p = 1.f;
    float t0 = 1.f, t1 = 1.f, t2 = 1.f, t3 = 1.f;
    const f32x4 zero = {0.f, 0.f, 0.f, 0.f};

    int4 Ba0, Ba1, Bb0, Bb1, Bc0, Bc1, Bd0, Bd1;

    // prime 4 banks (8 loads outstanding)
    {
        int p0, p1, p2, p3;
        if (wid == 0) { p0 = idxs[0];   p1 = idxs[1];   p2 = idxs[2];   p3 = idxs[3];   }
        else          { p0 = idxs[255]; p1 = idxs[254]; p2 = idxs[253]; p3 = idxs[252]; }
        LOAD2(Ba0, Ba1, p0);
        LOAD2(Bb0, Bb1, p1);
        LOAD2(Bc0, Bc1, p2);
        LOAD2(Bd0, Bd1, p3);
    }
    int4 mqc;
    {
        const int4 raw = *(const int4*)&idxs[wid ? 248 : 4];
        mqc = wid ? make_int4(raw.w, raw.z, raw.y, raw.x) : raw;
    }

#pragma unroll 1
    for (int I = 0; I < 32; ++I) {
        const int4 raw = *(const int4*)&idxs[wid ? (244 - 4 * I) : (4 * I + 8)];
        const int4 mq_nx = wid ? make_int4(raw.w, raw.z, raw.y, raw.x) : raw;

        TTSTEP(Ba0, Ba1, mqc.x);
        TTSTEP(Bb0, Bb1, mqc.y);
        TTSTEP(Bc0, Bc1, mqc.z);
        TTSTEP(Bd0, Bd1, mqc.w);

        // pipelined drift correction (1 shuffle-stage/iter, 16-lane groups);
        // all scales exact powers of two, exponents banked in Ecorr.
        float m1 = fmaxf(za_p, t0);
        float m2 = fmaxf(m1_p, t1);
        float m3 = fmaxf(m2_p, t2);
        const float m4 = fmaxf(m3_p, t3);
        const int eb = __float_as_int(m4) & 0x7f800000;
        const float s = __int_as_float(0x7F000000 - eb);
        v_lo *= s; v_hi *= s;
        Ecorr += (eb >> 23) - 127;
        const float zan = fmaxf(fabsf(v_lo), fabsf(v_hi));
        m1 *= s; m2 *= s; m3 *= s;
        t0 = __shfl_xor(zan, 1);
        t1 = __shfl_xor(m1, 2);
        t2 = __shfl_xor(m2, 4);
        t3 = __shfl_xor(m3, 8);
        za_p = zan; m1_p = m1; m2_p = m2; m3_p = m3;

        mqc = mq_nx;
    }

    // drain asm loads before any wave can end (round-3 lesson)
    asm volatile("s_waitcnt vmcnt(0)" ::: "memory");

    if (wid == 1) {
        if (lane < 16) { vbl[lane] = v_lo; vbh[lane] = v_hi; }
        if (lane == 0) ecred = Ecorr;
    }
    __syncthreads();

    if (wid == 0) {
        float p = v_lo * vbl[jj] + v_hi * vbh[jj];
        p += __shfl_xor(p, 1);
        p += __shfl_xor(p, 2);
        p += __shfl_xor(p, 4);
        p += __shfl_xor(p, 8);
        if (lane == 0) {
            const float S = (float)(Ecorr + ecred + kred[0] + kred[1]);
            out[b] = 2.0f * (S * 0.6931471805599453f + logf(fabsf(p)));
        }
    }
}

extern "C" void kernel_launch(void* const* d_in, const int* in_sizes, int n_in,
                              void* d_out, int out_size, void* d_ws, size_t ws_size,
                              hipStream_t stream)
{
    const int*   X    = (const int*)d_in[0];
    const float* core = (const float*)d_in[1];
    const float* Lb   = (const float*)d_in[2];
    const float* Rb   = (const float*)d_in[3];
    float* out = (float*)d_out;

    tt_quad_kernel<<<dim3(256), dim3(64), 0, stream>>>(core);
    tt_main_kernel<<<dim3(256), dim3(128), 0, stream>>>(X, Lb, Rb, out);
}

// Round 9
// 29.154 us; speedup vs baseline: 4.0365x; 1.1602x over previous
//
#include <hip/hip_runtime.h>
#include <math.h>

// Tensor-train log-likelihood, B=256, T=1024, d=4, D=32.
// Round 9: segment-parallel chain. 8 waves/seq: wave0 = Lb-vector fwd over
// quads [0,44); waves1-6 = 32x32 matrix products of 28 quads each (4 MFMAs
// per step, D->A transpose through per-wave LDS); wave7 = Rb-vector bwd over
// [212,256). Epilogue folds v_fwd @ M1..M6 @ v_bwd. Exact pow-2 exponent
// bookkeeping throughout (Ecorr incremented at scale APPLICATION, so the
// LDS-resident M frame always matches Ecorr). Same vmcnt discipline as
// round 8 (8 outstanding, wait 6, drain 0 before s_endpgm).

#define TT_B 256
#define TT_T 1024

typedef __attribute__((ext_vector_type(8))) short bf16x8;
typedef __attribute__((ext_vector_type(4))) float f32x4;

// Merged fragment table: [dir][m][H][lane] = uint4 (8 bf16, slots paired
// (2s,2s+1)). dir 0 = fwd (Q), dir 1 = bwd (Q^T). dir stride 512KB = 1<<19.
__device__ uint4 g_QT[2 * 256 * 2 * 64];
__device__ int   g_kQ[256];

__device__ __forceinline__ unsigned pkbf16(float lo, float hi)
{
    unsigned r;
    asm volatile("v_cvt_pk_bf16_f32 %0, %1, %2" : "=v"(r) : "v"(lo), "v"(hi));
    return r;
}

__device__ __forceinline__ bf16x8 as_bf16x8(int4 v)
{
    union { int4 i; bf16x8 h; } u; u.i = v; return u.h;
}

// ---- quad-product precompute (unchanged from round 8) ---------------------

__device__ __forceinline__ void mm32(const float* __restrict__ AT,
                                     const float* __restrict__ B,
                                     int h, int j, float c[16])
{
#pragma unroll
    for (int r = 0; r < 16; ++r) c[r] = 0.f;
#pragma unroll 4
    for (int k = 0; k < 32; ++k) {
        float bv = B[k * 32 + j];
        const float4* ar = (const float4*)(AT + k * 36 + 16 * h);
        float4 a0 = ar[0], a1 = ar[1], a2 = ar[2], a3 = ar[3];
        c[ 0] = fmaf(a0.x, bv, c[ 0]); c[ 1] = fmaf(a0.y, bv, c[ 1]);
        c[ 2] = fmaf(a0.z, bv, c[ 2]); c[ 3] = fmaf(a0.w, bv, c[ 3]);
        c[ 4] = fmaf(a1.x, bv, c[ 4]); c[ 5] = fmaf(a1.y, bv, c[ 5]);
        c[ 6] = fmaf(a1.z, bv, c[ 6]); c[ 7] = fmaf(a1.w, bv, c[ 7]);
        c[ 8] = fmaf(a2.x, bv, c[ 8]); c[ 9] = fmaf(a2.y, bv, c[ 9]);
        c[10] = fmaf(a2.z, bv, c[10]); c[11] = fmaf(a2.w, bv, c[11]);
        c[12] = fmaf(a3.x, bv, c[12]); c[13] = fmaf(a3.y, bv, c[13]);
        c[14] = fmaf(a3.z, bv, c[14]); c[15] = fmaf(a3.w, bv, c[15]);
    }
}

__device__ __forceinline__ void load_transpose(const float* __restrict__ src,
                                               float* __restrict__ dstT, int lane)
{
    const float4* s4 = (const float4*)src;
    float4 v0 = s4[lane * 4 + 0], v1 = s4[lane * 4 + 1];
    float4 v2 = s4[lane * 4 + 2], v3 = s4[lane * 4 + 3];
    const int ro = lane >> 1;
    const int k0 = (lane & 1) * 16;
    dstT[(k0 +  0) * 36 + ro] = v0.x; dstT[(k0 +  1) * 36 + ro] = v0.y;
    dstT[(k0 +  2) * 36 + ro] = v0.z; dstT[(k0 +  3) * 36 + ro] = v0.w;
    dstT[(k0 +  4) * 36 + ro] = v1.x; dstT[(k0 +  5) * 36 + ro] = v1.y;
    dstT[(k0 +  6) * 36 + ro] = v1.z; dstT[(k0 +  7) * 36 + ro] = v1.w;
    dstT[(k0 +  8) * 36 + ro] = v2.x; dstT[(k0 +  9) * 36 + ro] = v2.y;
    dstT[(k0 + 10) * 36 + ro] = v2.z; dstT[(k0 + 11) * 36 + ro] = v2.w;
    dstT[(k0 + 12) * 36 + ro] = v3.x; dstT[(k0 + 13) * 36 + ro] = v3.y;
    dstT[(k0 + 14) * 36 + ro] = v3.z; dstT[(k0 + 15) * 36 + ro] = v3.w;
}

__device__ __forceinline__ void load_straight(const float* __restrict__ src,
                                              float* __restrict__ dst, int lane)
{
    const float4* s4 = (const float4*)src;
    float4* d4 = (float4*)dst;
    d4[lane * 4 + 0] = s4[lane * 4 + 0];
    d4[lane * 4 + 1] = s4[lane * 4 + 1];
    d4[lane * 4 + 2] = s4[lane * 4 + 2];
    d4[lane * 4 + 3] = s4[lane * 4 + 3];
}

__global__ __launch_bounds__(64) void tt_quad_kernel(const float* __restrict__ core)
{
    __shared__ float AT [32 * 36];
    __shared__ float Bb [32 * 32];
    __shared__ float A2T[32 * 36];
    __shared__ float B2 [32 * 32];
    __shared__ float Qs [32 * 33];

    const int m    = blockIdx.x;
    const int lane = threadIdx.x;
    const int h    = lane >> 5;
    const int j    = lane & 31;

    const int ia = (m >> 6) & 3;
    const int ib = (m >> 4) & 3;
    const int ic = (m >> 2) & 3;
    const int id =  m       & 3;

    float c[16];

    load_transpose(core + ia * 1024, AT, lane);
    load_straight (core + ib * 1024, Bb, lane);
    __syncthreads();
    mm32(AT, Bb, h, j, c);
    __syncthreads();
    {
        float4* dst = (float4*)(A2T + j * 36 + 16 * h);
        dst[0] = make_float4(c[ 0], c[ 1], c[ 2], c[ 3]);
        dst[1] = make_float4(c[ 4], c[ 5], c[ 6], c[ 7]);
        dst[2] = make_float4(c[ 8], c[ 9], c[10], c[11]);
        dst[3] = make_float4(c[12], c[13], c[14], c[15]);
    }
    __syncthreads();

    load_transpose(core + ic * 1024, AT, lane);
    load_straight (core + id * 1024, Bb, lane);
    __syncthreads();
    mm32(AT, Bb, h, j, c);
    __syncthreads();
#pragma unroll
    for (int r = 0; r < 16; ++r) B2[(16 * h + r) * 32 + j] = c[r];
    __syncthreads();

    mm32(A2T, B2, h, j, c);

    float ssum = 0.f;
#pragma unroll
    for (int r = 0; r < 16; ++r) ssum += fabsf(c[r]);
    ssum += __shfl_xor(ssum, 32);
    float cm = ssum;
    cm = fmaxf(cm, __shfl_xor(cm,  1));
    cm = fmaxf(cm, __shfl_xor(cm,  2));
    cm = fmaxf(cm, __shfl_xor(cm,  4));
    cm = fmaxf(cm, __shfl_xor(cm,  8));
    cm = fmaxf(cm, __shfl_xor(cm, 16));
    const int eb = __float_as_int(cm) & 0x7f800000;
    const float s = __int_as_float(0x7F000000 - eb);   // 2^-(E-127), exact
#pragma unroll
    for (int r = 0; r < 16; ++r) c[r] *= s;
    if (lane == 0) g_kQ[m] = (eb >> 23) - 127;

#pragma unroll
    for (int r = 0; r < 16; ++r) Qs[(16 * h + r) * 33 + j] = c[r];
    __syncthreads();

    const int g  = lane >> 4;
    const int jj = lane & 15;
#pragma unroll
    for (int H = 0; H < 2; ++H) {
        uint4 wf;
        wf.x = pkbf16(Qs[(8*g+0)*33 + 16*H+jj], Qs[(8*g+1)*33 + 16*H+jj]);
        wf.y = pkbf16(Qs[(8*g+2)*33 + 16*H+jj], Qs[(8*g+3)*33 + 16*H+jj]);
        wf.z = pkbf16(Qs[(8*g+4)*33 + 16*H+jj], Qs[(8*g+5)*33 + 16*H+jj]);
        wf.w = pkbf16(Qs[(8*g+6)*33 + 16*H+jj], Qs[(8*g+7)*33 + 16*H+jj]);
        g_QT[(m * 2 + H) * 64 + lane] = wf;
        const float* rp = &Qs[(16*H + jj) * 33];
        uint4 wb;
        wb.x = pkbf16(rp[8*g+0], rp[8*g+1]);
        wb.y = pkbf16(rp[8*g+2], rp[8*g+3]);
        wb.z = pkbf16(rp[8*g+4], rp[8*g+5]);
        wb.w = pkbf16(rp[8*g+6], rp[8*g+7]);
        g_QT[32768 + (m * 2 + H) * 64 + lane] = wb;
    }
}

// ---- main kernel -----------------------------------------------------------

#define LOAD2(UB0, UB1, MIDX) do {                                            \
    const int voff_ = (tabof | ((MIDX) << 11) | (lane << 4));                 \
    asm volatile("global_load_dwordx4 %0, %1, %2"             : "=v"(UB0) : "v"(voff_), "s"(qtb)); \
    asm volatile("global_load_dwordx4 %0, %1, %2 offset:1024" : "=v"(UB1) : "v"(voff_), "s"(qtb)); \
} while (0)

// vector step (validated round 8)
#define TTSTEP(UB0, UB1, MIDX) do {                                           \
    const float srcv_ = hisel ? v_hi : v_lo;                                  \
    const int sb_ = __float_as_int(srcv_);                                    \
    const int r0_ = __builtin_amdgcn_ds_bpermute(a0 +  0, sb_);               \
    const int r1_ = __builtin_amdgcn_ds_bpermute(a0 +  4, sb_);               \
    const int r2_ = __builtin_amdgcn_ds_bpermute(a0 +  8, sb_);               \
    const int r3_ = __builtin_amdgcn_ds_bpermute(a0 + 12, sb_);               \
    const int r4_ = __builtin_amdgcn_ds_bpermute(a0 + 16, sb_);               \
    const int r5_ = __builtin_amdgcn_ds_bpermute(a0 + 20, sb_);               \
    const int r6_ = __builtin_amdgcn_ds_bpermute(a0 + 24, sb_);               \
    const int r7_ = __builtin_amdgcn_ds_bpermute(a0 + 28, sb_);               \
    int4 aw_;                                                                 \
    aw_.x = (int)pkbf16(__int_as_float(r0_), __int_as_float(r1_));            \
    aw_.y = (int)pkbf16(__int_as_float(r2_), __int_as_float(r3_));            \
    aw_.z = (int)pkbf16(__int_as_float(r4_), __int_as_float(r5_));            \
    aw_.w = (int)pkbf16(__int_as_float(r6_), __int_as_float(r7_));            \
    const bf16x8 af_ = as_bf16x8(aw_);                                        \
    const bf16x8 bf0_ = as_bf16x8(UB0);                                       \
    const bf16x8 bf1_ = as_bf16x8(UB1);                                       \
    asm volatile("s_waitcnt vmcnt(6)" ::: "memory");                          \
    __builtin_amdgcn_sched_barrier(0);                                        \
    const f32x4 d1_ = __builtin_amdgcn_mfma_f32_16x16x32_bf16(af_, bf0_, zero, 0, 0, 0); \
    const f32x4 d2_ = __builtin_amdgcn_mfma_f32_16x16x32_bf16(af_, bf1_, zero, 0, 0, 0); \
    LOAD2(UB0, UB1, (MIDX));                                                  \
    v_lo = d1_[0];                                                            \
    v_hi = d2_[0];                                                            \
} while (0)

// matrix step: M <- M @ Q. D layout (m89): col=lane&15, row=(lane>>4)*4+reg.
// Write D to LDS M[r][c] (stride 36), fence, read A-frags (row p / 16+p,
// cols 8q..8q+7), scale by s_apply (pow-2; Ecorr counted at application),
// pack to bf16. DOZA: also record max|elem| (the 64 lanes' reads tile M
// exactly once).
#define MSTEP(UB0, UB1, MIDX, DOZA) do {                                      \
    const bf16x8 bf0_ = as_bf16x8(UB0);                                       \
    const bf16x8 bf1_ = as_bf16x8(UB1);                                       \
    asm volatile("s_waitcnt vmcnt(6)" ::: "memory");                          \
    __builtin_amdgcn_sched_barrier(0);                                        \
    const f32x4 d00_ = __builtin_amdgcn_mfma_f32_16x16x32_bf16(af0, bf0_, zero, 0, 0, 0); \
    const f32x4 d01_ = __builtin_amdgcn_mfma_f32_16x16x32_bf16(af0, bf1_, zero, 0, 0, 0); \
    const f32x4 d10_ = __builtin_amdgcn_mfma_f32_16x16x32_bf16(af1, bf0_, zero, 0, 0, 0); \
    const f32x4 d11_ = __builtin_amdgcn_mfma_f32_16x16x32_bf16(af1, bf1_, zero, 0, 0, 0); \
    LOAD2(UB0, UB1, (MIDX));                                                  \
    {                                                                         \
        float* w0_ = Mw + (4 * q) * 36 + p;                                   \
        w0_[0*36] = d00_[0]; w0_[1*36] = d00_[1];                             \
        w0_[2*36] = d00_[2]; w0_[3*36] = d00_[3];                             \
        w0_[0*36+16] = d01_[0]; w0_[1*36+16] = d01_[1];                       \
        w0_[2*36+16] = d01_[2]; w0_[3*36+16] = d01_[3];                       \
        float* w2_ = Mw + (16 + 4 * q) * 36 + p;                              \
        w2_[0*36] = d10_[0]; w2_[1*36] = d10_[1];                             \
        w2_[2*36] = d10_[2]; w2_[3*36] = d10_[3];                             \
        w2_[0*36+16] = d11_[0]; w2_[1*36+16] = d11_[1];                       \
        w2_[2*36+16] = d11_[2]; w2_[3*36+16] = d11_[3];                       \
    }                                                                         \
    asm volatile("s_waitcnt lgkmcnt(0)" ::: "memory");                        \
    __builtin_amdgcn_sched_barrier(0);                                        \
    const float4 a00_ = *(const float4*)(Mw + p * 36 + 8 * q);                \
    const float4 a01_ = *(const float4*)(Mw + p * 36 + 8 * q + 4);            \
    const float4 a10_ = *(const float4*)(Mw + (16 + p) * 36 + 8 * q);         \
    const float4 a11_ = *(const float4*)(Mw + (16 + p) * 36 + 8 * q + 4);     \
    const float f0_ = a00_.x * s_apply, f1_ = a00_.y * s_apply;               \
    const float f2_ = a00_.z * s_apply, f3_ = a00_.w * s_apply;               \
    const float f4_ = a01_.x * s_apply, f5_ = a01_.y * s_apply;               \
    const float f6_ = a01_.z * s_apply, f7_ = a01_.w * s_apply;               \
    const float g0_ = a10_.x * s_apply, g1_ = a10_.y * s_apply;               \
    const float g2_ = a10_.z * s_apply, g3_ = a10_.w * s_apply;               \
    const float g4_ = a11_.x * s_apply, g5_ = a11_.y * s_apply;               \
    const float g6_ = a11_.z * s_apply, g7_ = a11_.w * s_apply;               \
    if (DOZA) {                                                               \
        float z0_ = fmaxf(fmaxf(fabsf(f0_), fabsf(f1_)), fmaxf(fabsf(f2_), fabsf(f3_))); \
        float z1_ = fmaxf(fmaxf(fabsf(f4_), fabsf(f5_)), fmaxf(fabsf(f6_), fabsf(f7_))); \
        float z2_ = fmaxf(fmaxf(fabsf(g0_), fabsf(g1_)), fmaxf(fabsf(g2_), fabsf(g3_))); \
        float z3_ = fmaxf(fmaxf(fabsf(g4_), fabsf(g5_)), fmaxf(fabsf(g6_), fabsf(g7_))); \
        za_meas = fmaxf(fmaxf(z0_, z1_), fmaxf(z2_, z3_));                    \
    }                                                                         \
    int4 aw0_, aw1_;                                                          \
    aw0_.x = (int)pkbf16(f0_, f1_); aw0_.y = (int)pkbf16(f2_, f3_);           \
    aw0_.z = (int)pkbf16(f4_, f5_); aw0_.w = (int)pkbf16(f6_, f7_);           \
    aw1_.x = (int)pkbf16(g0_, g1_); aw1_.y = (int)pkbf16(g2_, g3_);           \
    aw1_.z = (int)pkbf16(g4_, g5_); aw1_.w = (int)pkbf16(g6_, g7_);           \
    af0 = as_bf16x8(aw0_);                                                    \
    af1 = as_bf16x8(aw1_);                                                    \
    Ecorr += 127 - ((__float_as_int(s_apply) >> 23) & 0xFF);                  \
    s_apply = 1.0f;                                                           \
} while (0)

__global__ __launch_bounds__(512, 1) void tt_main_kernel(const int* __restrict__ X,
                                                         const float* __restrict__ Lb,
                                                         const float* __restrict__ Rb,
                                                         float* __restrict__ out)
{
    __shared__ int idxs[256];
    __shared__ __align__(16) float Mb[6 * 1152];   // 6 x [32][36] f32
    __shared__ float comb_f[32], comb_b[32], sc[32];
    __shared__ int Ec[8];
    __shared__ int kpart[8];

    const int b    = blockIdx.x;
    const int tid  = threadIdx.x;
    const int wid  = tid >> 6;
    const int lane = tid & 63;

    // quad indices + table-exponent partial sums (threads 0..255)
    int ksum = 0;
    if (tid < 256) {
        const int4* Xq = (const int4*)(X + (size_t)b * TT_T);
        const int4 xv = Xq[tid];
        const int m = ((xv.x * 4 + xv.y) * 4 + xv.z) * 4 + xv.w;
        idxs[tid] = m;
        ksum = g_kQ[m];
    }
    ksum += __shfl_xor(ksum,  1);
    ksum += __shfl_xor(ksum,  2);
    ksum += __shfl_xor(ksum,  4);
    ksum += __shfl_xor(ksum,  8);
    ksum += __shfl_xor(ksum, 16);
    ksum += __shfl_xor(ksum, 32);
    if (lane == 0) kpart[wid] = ksum;
    __syncthreads();

    const uint4* qtb = g_QT;                   // compile-time global -> SGPR
    const f32x4 zero = {0.f, 0.f, 0.f, 0.f};
    int Ecorr = 0;

    if (wid == 0 || wid == 7) {
        // ---- vector segments: wid 0 fwd quads [0,44), wid 7 bwd [212,256)
        const int  vw    = (wid == 7);
        const int  tabof = vw << 19;
        const float* vsrc = vw ? Rb : Lb;
        const int jj = lane & 15;
        float v_lo = vsrc[jj];
        float v_hi = vsrc[16 + jj];
        const bool hisel = ((lane & 48) == 16);
        const int  a0    = ((lane >> 4) & 1) * 32 + ((lane >> 5) & 1) * 64;

        float za_p = 1.f, m1_p = 1.f, m2_p = 1.f, m3_p = 1.f;
        float t0 = 1.f, t1 = 1.f, t2 = 1.f, t3 = 1.f;

        int4 Ba0, Ba1, Bb0, Bb1, Bc0, Bc1, Bd0, Bd1;
        {
            int p0, p1, p2, p3;
            if (!vw) { p0 = idxs[0];   p1 = idxs[1];   p2 = idxs[2];   p3 = idxs[3];   }
            else     { p0 = idxs[255]; p1 = idxs[254]; p2 = idxs[253]; p3 = idxs[252]; }
            LOAD2(Ba0, Ba1, p0);
            LOAD2(Bb0, Bb1, p1);
            LOAD2(Bc0, Bc1, p2);
            LOAD2(Bd0, Bd1, p3);
        }
        int4 mqc;
        {
            const int4 raw = *(const int4*)&idxs[vw ? 248 : 4];
            mqc = vw ? make_int4(raw.w, raw.z, raw.y, raw.x) : raw;
        }

#pragma unroll 1
        for (int I = 0; I < 11; ++I) {          // 44 steps
            const int4 raw = *(const int4*)&idxs[vw ? (244 - 4 * I) : (4 * I + 8)];
            const int4 mq_nx = vw ? make_int4(raw.w, raw.z, raw.y, raw.x) : raw;

            TTSTEP(Ba0, Ba1, mqc.x);
            TTSTEP(Bb0, Bb1, mqc.y);
            TTSTEP(Bc0, Bc1, mqc.z);
            TTSTEP(Bd0, Bd1, mqc.w);

            float m1 = fmaxf(za_p, t0);
            float m2 = fmaxf(m1_p, t1);
            float m3 = fmaxf(m2_p, t2);
            const float m4 = fmaxf(m3_p, t3);
            const int eb = __float_as_int(m4) & 0x7f800000;
            const float s = __int_as_float(0x7F000000 - eb);
            v_lo *= s; v_hi *= s;
            Ecorr += (eb >> 23) - 127;
            const float zan = fmaxf(fabsf(v_lo), fabsf(v_hi));
            m1 *= s; m2 *= s; m3 *= s;
            t0 = __shfl_xor(zan, 1);
            t1 = __shfl_xor(m1, 2);
            t2 = __shfl_xor(m2, 4);
            t3 = __shfl_xor(m3, 8);
            za_p = zan; m1_p = m1; m2_p = m2; m3_p = m3;

            mqc = mq_nx;
        }

        asm volatile("s_waitcnt vmcnt(0)" ::: "memory");   // round-3 lesson

        if (lane < 16) {
            float* cb = vw ? comb_b : comb_f;
            cb[lane] = v_lo;
            cb[16 + lane] = v_hi;
        }
        if (lane == 0) Ec[wid] = Ecorr;
    } else {
        // ---- matrix segments: wid k in 1..6, quads [44+28(k-1), 44+28k)
        const int tabof = 0;
        const int mbase = 44 + 28 * (wid - 1);
        float* Mw = Mb + (wid - 1) * 1152;
        const int p = lane & 15;
        const int q = lane >> 4;

        // identity A-fragments in slot-space (valid for any true lane->k map:
        // MFMA contracts A/B slot-wise, and the B table uses the same map)
        bf16x8 af0, af1;
        {
            int4 aw0, aw1;
            int* w0 = (int*)&aw0;
            int* w1 = (int*)&aw1;
#pragma unroll
            for (int t = 0; t < 4; ++t) {
                const unsigned lo0 = (8 * q + 2 * t     == p)      ? 0x3F80u : 0u;
                const unsigned hi0 = (8 * q + 2 * t + 1 == p)      ? 0x3F80u : 0u;
                const unsigned lo1 = (8 * q + 2 * t     == 16 + p) ? 0x3F80u : 0u;
                const unsigned hi1 = (8 * q + 2 * t + 1 == 16 + p) ? 0x3F80u : 0u;
                w0[t] = (int)(lo0 | (hi0 << 16));
                w1[t] = (int)(lo1 | (hi1 << 16));
            }
            af0 = as_bf16x8(aw0);
            af1 = as_bf16x8(aw1);
        }

        float s_apply = 1.0f, za_meas = 1.0f;
        float za_p = 1.f, m1_p = 1.f, m2_p = 1.f, m3_p = 1.f, m4_p = 1.f, m5_p = 1.f;
        float t0 = 1.f, t1 = 1.f, t2 = 1.f, t3 = 1.f, t4 = 1.f, t5 = 1.f;

        int4 Ba0, Ba1, Bb0, Bb1, Bc0, Bc1, Bd0, Bd1;
        LOAD2(Ba0, Ba1, idxs[mbase + 0]);
        LOAD2(Bb0, Bb1, idxs[mbase + 1]);
        LOAD2(Bc0, Bc1, idxs[mbase + 2]);
        LOAD2(Bd0, Bd1, idxs[mbase + 3]);
        int4 mqc = *(const int4*)&idxs[mbase + 4];

#pragma unroll 1
        for (int I = 0; I < 7; ++I) {           // 28 steps
            const int4 mq_nx = *(const int4*)&idxs[mbase + 4 * I + 8];

            MSTEP(Ba0, Ba1, mqc.x, 0);
            MSTEP(Bb0, Bb1, mqc.y, 0);
            MSTEP(Bc0, Bc1, mqc.z, 0);
            MSTEP(Bd0, Bd1, mqc.w, 1);

            // 6-stage pipelined drift correction (64-lane max)
            float m1 = fmaxf(za_p, t0);
            float m2 = fmaxf(m1_p, t1);
            float m3 = fmaxf(m2_p, t2);
            float m4 = fmaxf(m3_p, t3);
            float m5 = fmaxf(m4_p, t4);
            const float m6 = fmaxf(m5_p, t5);
            const int eb = __float_as_int(m6) & 0x7f800000;
            const float s = __int_as_float(0x7F000000 - eb);
            s_apply = s;                       // applied + counted next MSTEP
            const float zan = za_meas * s;
            m1 *= s; m2 *= s; m3 *= s; m4 *= s; m5 *= s;
            t0 = __shfl_xor(zan, 1);
            t1 = __shfl_xor(m1, 2);
            t2 = __shfl_xor(m2, 4);
            t3 = __shfl_xor(m3, 8);
            t4 = __shfl_xor(m4, 16);
            t5 = __shfl_xor(m5, 32);
            za_p = zan; m1_p = m1; m2_p = m2; m3_p = m3; m4_p = m4; m5_p = m5;

            mqc = mq_nx;
        }

        asm volatile("s_waitcnt vmcnt(0)" ::: "memory");   // round-3 lesson
        // final M is in Mw (written by the last MSTEP), frame == Ecorr
        if (lane == 0) Ec[wid] = Ecorr;
    }
    __syncthreads();

    // ---- epilogue: v_fwd @ M1..M6 @ v_bwd (wave 0, lanes 0..31) ----------
    if (wid == 0 && lane < 32) {
        float vv = comb_f[lane];
#pragma unroll 1
        for (int k = 0; k < 6; ++k) {
            sc[lane] = vv;
            asm volatile("s_waitcnt lgkmcnt(0)" ::: "memory");
            __builtin_amdgcn_sched_barrier(0);
            const float* Mk = Mb + k * 1152;
            float nv = 0.f;
#pragma unroll 8
            for (int i = 0; i < 32; ++i) nv = fmaf(sc[i], Mk[i * 36 + lane], nv);
            asm volatile("s_waitcnt lgkmcnt(0)" ::: "memory");
            __builtin_amdgcn_sched_barrier(0);
            vv = nv;
        }
        float pp = vv * comb_b[lane];
        pp += __shfl_xor(pp,  1);
        pp += __shfl_xor(pp,  2);
        pp += __shfl_xor(pp,  4);
        pp += __shfl_xor(pp,  8);
        pp += __shfl_xor(pp, 16);
        if (lane == 0) {
            int S = 0;
#pragma unroll
            for (int w = 0; w < 8; ++w) S += Ec[w] + kpart[w];
            out[b] = 2.0f * ((float)S * 0.6931471805599453f + logf(fabsf(pp)));
        }
    }
}

extern "C" void kernel_launch(void* const* d_in, const int* in_sizes, int n_in,
                              void* d_out, int out_size, void* d_ws, size_t ws_size,
                              hipStream_t stream)
{
    const int*   X    = (const int*)d_in[0];
    const float* core = (const float*)d_in[1];
    const float* Lb   = (const float*)d_in[2];
    const float* Rb   = (const float*)d_in[3];
    float* out = (float*)d_out;

    tt_quad_kernel<<<dim3(256), dim3(64), 0, stream>>>(core);
    tt_main_kernel<<<dim3(256), dim3(512), 0, stream>>>(X, Lb, Rb, out);
}

// Round 13
// 27.635 us; speedup vs baseline: 4.2584x; 1.0550x over previous
//
#include <hip/hip_runtime.h>
#include <math.h>

// Tensor-train log-likelihood, B=256, T=1024, d=4, D=32.
// Round 13: bisect round-12. KEEP the zero-DS sigma-map fragment segment
// chain (8 waves x 32 quads, 4 MFMA/step, pack via 8 pkbf16). REPLACE the
// tree's bit-surgery with r9-validated LDS mechanics: each segment's LAST
// step writes its f32 D quadrants directly to LDS (m89 physical layout,
// sigma-free interface); tree nodes read A-frags (float4+pkbf16, r9 motif)
// and B-frags (scalar reads+pkbf16, r8 table motif) under the STANDARD
// k-map (cancellation on both sides), write f32 results back (m89 layout).
// Epilogue: plain VALU fold (r9 column-read motif). Exact pow-2 rescales;
// exponents summed. No inline-asm loads anywhere; only pkbf16 asm remains.

#define TT_B 256
#define TT_T 1024

typedef __attribute__((ext_vector_type(8))) short bf16x8;
typedef __attribute__((ext_vector_type(4))) float f32x4;

// Fragment table: [m][H][lane] = uint4; lane (g=lane>>4, jj=lane&15),
// slot s holds Qs[sigma(g,s)][16H+jj], sigma(g,s)=4g+(s&3)+16*(s>>2),
// slots paired (2t,2t+1) per word.
__device__ uint4 g_QT[256 * 2 * 64];
__device__ int   g_kQ[256];

__device__ __forceinline__ unsigned pkbf16(float lo, float hi)
{
    unsigned r;
    asm volatile("v_cvt_pk_bf16_f32 %0, %1, %2" : "=v"(r) : "v"(lo), "v"(hi));
    return r;
}
__device__ __forceinline__ bf16x8 as_bf16x8(int4 v)
{ union { int4 i; bf16x8 h; } u; u.i = v; return u.h; }
__device__ __forceinline__ bf16x8 as_bf16x8u(uint4 v)
{ union { uint4 i; bf16x8 h; } u; u.i = v; return u.h; }

// ---- quad-product precompute (r12 verbatim) -------------------------------

__device__ __forceinline__ void mm32(const float* __restrict__ AT,
                                     const float* __restrict__ B,
                                     int h, int j, float c[16])
{
#pragma unroll
    for (int r = 0; r < 16; ++r) c[r] = 0.f;
#pragma unroll 4
    for (int k = 0; k < 32; ++k) {
        float bv = B[k * 32 + j];
        const float4* ar = (const float4*)(AT + k * 36 + 16 * h);
        float4 a0 = ar[0], a1 = ar[1], a2 = ar[2], a3 = ar[3];
        c[ 0] = fmaf(a0.x, bv, c[ 0]); c[ 1] = fmaf(a0.y, bv, c[ 1]);
        c[ 2] = fmaf(a0.z, bv, c[ 2]); c[ 3] = fmaf(a0.w, bv, c[ 3]);
        c[ 4] = fmaf(a1.x, bv, c[ 4]); c[ 5] = fmaf(a1.y, bv, c[ 5]);
        c[ 6] = fmaf(a1.z, bv, c[ 6]); c[ 7] = fmaf(a1.w, bv, c[ 7]);
        c[ 8] = fmaf(a2.x, bv, c[ 8]); c[ 9] = fmaf(a2.y, bv, c[ 9]);
        c[10] = fmaf(a2.z, bv, c[10]); c[11] = fmaf(a2.w, bv, c[11]);
        c[12] = fmaf(a3.x, bv, c[12]); c[13] = fmaf(a3.y, bv, c[13]);
        c[14] = fmaf(a3.z, bv, c[14]); c[15] = fmaf(a3.w, bv, c[15]);
    }
}

__device__ __forceinline__ void load_transpose(const float* __restrict__ src,
                                               float* __restrict__ dstT, int lane)
{
    const float4* s4 = (const float4*)src;
    float4 v0 = s4[lane * 4 + 0], v1 = s4[lane * 4 + 1];
    float4 v2 = s4[lane * 4 + 2], v3 = s4[lane * 4 + 3];
    const int ro = lane >> 1;
    const int k0 = (lane & 1) * 16;
    dstT[(k0 +  0) * 36 + ro] = v0.x; dstT[(k0 +  1) * 36 + ro] = v0.y;
    dstT[(k0 +  2) * 36 + ro] = v0.z; dstT[(k0 +  3) * 36 + ro] = v0.w;
    dstT[(k0 +  4) * 36 + ro] = v1.x; dstT[(k0 +  5) * 36 + ro] = v1.y;
    dstT[(k0 +  6) * 36 + ro] = v1.z; dstT[(k0 +  7) * 36 + ro] = v1.w;
    dstT[(k0 +  8) * 36 + ro] = v2.x; dstT[(k0 +  9) * 36 + ro] = v2.y;
    dstT[(k0 + 10) * 36 + ro] = v2.z; dstT[(k0 + 11) * 36 + ro] = v2.w;
    dstT[(k0 + 12) * 36 + ro] = v3.x; dstT[(k0 + 13) * 36 + ro] = v3.y;
    dstT[(k0 + 14) * 36 + ro] = v3.z; dstT[(k0 + 15) * 36 + ro] = v3.w;
}

__device__ __forceinline__ void load_straight(const float* __restrict__ src,
                                              float* __restrict__ dst, int lane)
{
    const float4* s4 = (const float4*)src;
    float4* d4 = (float4*)dst;
    d4[lane * 4 + 0] = s4[lane * 4 + 0];
    d4[lane * 4 + 1] = s4[lane * 4 + 1];
    d4[lane * 4 + 2] = s4[lane * 4 + 2];
    d4[lane * 4 + 3] = s4[lane * 4 + 3];
}

__global__ __launch_bounds__(64) void tt_quad_kernel(const float* __restrict__ core)
{
    __shared__ float AT [32 * 36];
    __shared__ float Bb [32 * 32];
    __shared__ float A2T[32 * 36];
    __shared__ float B2 [32 * 32];
    __shared__ float Qs [32 * 33];

    const int m    = blockIdx.x;
    const int lane = threadIdx.x;
    const int h    = lane >> 5;
    const int j    = lane & 31;

    const int ia = (m >> 6) & 3;
    const int ib = (m >> 4) & 3;
    const int ic = (m >> 2) & 3;
    const int id =  m       & 3;

    float c[16];

    load_transpose(core + ia * 1024, AT, lane);
    load_straight (core + ib * 1024, Bb, lane);
    __syncthreads();
    mm32(AT, Bb, h, j, c);
    __syncthreads();
    {
        float4* dst = (float4*)(A2T + j * 36 + 16 * h);
        dst[0] = make_float4(c[ 0], c[ 1], c[ 2], c[ 3]);
        dst[1] = make_float4(c[ 4], c[ 5], c[ 6], c[ 7]);
        dst[2] = make_float4(c[ 8], c[ 9], c[10], c[11]);
        dst[3] = make_float4(c[12], c[13], c[14], c[15]);
    }
    __syncthreads();

    load_transpose(core + ic * 1024, AT, lane);
    load_straight (core + id * 1024, Bb, lane);
    __syncthreads();
    mm32(AT, Bb, h, j, c);
    __syncthreads();
#pragma unroll
    for (int r = 0; r < 16; ++r) B2[(16 * h + r) * 32 + j] = c[r];
    __syncthreads();

    mm32(A2T, B2, h, j, c);

    // normalize: k = floor(log2(max_j col-abs-sum)), Q *= 2^-k (exact)
    float ssum = 0.f;
#pragma unroll
    for (int r = 0; r < 16; ++r) ssum += fabsf(c[r]);
    ssum += __shfl_xor(ssum, 32);
    float cm = ssum;
    cm = fmaxf(cm, __shfl_xor(cm,  1));
    cm = fmaxf(cm, __shfl_xor(cm,  2));
    cm = fmaxf(cm, __shfl_xor(cm,  4));
    cm = fmaxf(cm, __shfl_xor(cm,  8));
    cm = fmaxf(cm, __shfl_xor(cm, 16));
    const int eb = __float_as_int(cm) & 0x7f800000;
    const float s = __int_as_float(0x7F000000 - eb);
#pragma unroll
    for (int r = 0; r < 16; ++r) c[r] *= s;
    if (lane == 0) g_kQ[m] = (eb >> 23) - 127;

#pragma unroll
    for (int r = 0; r < 16; ++r) Qs[(16 * h + r) * 33 + j] = c[r];
    __syncthreads();

    // emit fragments under sigma(g,s) = 4g + (s&3) + 16*(s>>2)
    const int g  = lane >> 4;
    const int jj = lane & 15;
#pragma unroll
    for (int H = 0; H < 2; ++H) {
        const int cb = 16 * H + jj;
        uint4 wf;
        wf.x = pkbf16(Qs[(4*g+0)*33 + cb],  Qs[(4*g+1)*33 + cb]);
        wf.y = pkbf16(Qs[(4*g+2)*33 + cb],  Qs[(4*g+3)*33 + cb]);
        wf.z = pkbf16(Qs[(16+4*g+0)*33 + cb], Qs[(16+4*g+1)*33 + cb]);
        wf.w = pkbf16(Qs[(16+4*g+2)*33 + cb], Qs[(16+4*g+3)*33 + cb]);
        g_QT[(m * 2 + H) * 64 + lane] = wf;
    }
}

// ---- main kernel -----------------------------------------------------------

#define MAXD4(D) fmaxf(fmaxf(fabsf(D[0]), fabsf(D[1])), fmaxf(fabsf(D[2]), fabsf(D[3])))

// tree node (r9-validated mechanics): combined = S_b x S_a, all f32 in LDS.
// A-frag (standard map) from M_b via float4 reads + pkbf16 (r9 MSTEP motif);
// B-frag (standard map) from M_a via scalar reads + pkbf16 (r8 table motif);
// result scaled by exact pow-2, written m89-layout to Mdst. Returns exponent.
__device__ __forceinline__ int tree_node_lds(const float* __restrict__ Ma,
                                             const float* __restrict__ Mb,
                                             float* __restrict__ Mdst, int lane)
{
    const int p = lane & 15, q = lane >> 4;
    // A = S_b: A[r][k] split in row halves; slot s of lane(q,p) = Mb[p][8q+s]
    const float4 a00 = *(const float4*)(Mb + p * 36 + 8 * q);
    const float4 a01 = *(const float4*)(Mb + p * 36 + 8 * q + 4);
    const float4 a10 = *(const float4*)(Mb + (16 + p) * 36 + 8 * q);
    const float4 a11 = *(const float4*)(Mb + (16 + p) * 36 + 8 * q + 4);
    int4 aw0, aw1;
    aw0.x = (int)pkbf16(a00.x, a00.y); aw0.y = (int)pkbf16(a00.z, a00.w);
    aw0.z = (int)pkbf16(a01.x, a01.y); aw0.w = (int)pkbf16(a01.z, a01.w);
    aw1.x = (int)pkbf16(a10.x, a10.y); aw1.y = (int)pkbf16(a10.z, a10.w);
    aw1.z = (int)pkbf16(a11.x, a11.y); aw1.w = (int)pkbf16(a11.z, a11.w);
    // B = S_a: slot s of lane(g=q, jj=p) = Ma[8q+s][p] (cols p / 16+p)
    int4 bw0, bw1;
    bw0.x = (int)pkbf16(Ma[(8*q+0)*36 + p], Ma[(8*q+1)*36 + p]);
    bw0.y = (int)pkbf16(Ma[(8*q+2)*36 + p], Ma[(8*q+3)*36 + p]);
    bw0.z = (int)pkbf16(Ma[(8*q+4)*36 + p], Ma[(8*q+5)*36 + p]);
    bw0.w = (int)pkbf16(Ma[(8*q+6)*36 + p], Ma[(8*q+7)*36 + p]);
    bw1.x = (int)pkbf16(Ma[(8*q+0)*36 + 16 + p], Ma[(8*q+1)*36 + 16 + p]);
    bw1.y = (int)pkbf16(Ma[(8*q+2)*36 + 16 + p], Ma[(8*q+3)*36 + 16 + p]);
    bw1.z = (int)pkbf16(Ma[(8*q+4)*36 + 16 + p], Ma[(8*q+5)*36 + 16 + p]);
    bw1.w = (int)pkbf16(Ma[(8*q+6)*36 + 16 + p], Ma[(8*q+7)*36 + 16 + p]);

    const bf16x8 af0 = as_bf16x8(aw0), af1 = as_bf16x8(aw1);
    const bf16x8 bf0 = as_bf16x8(bw0), bf1 = as_bf16x8(bw1);
    const f32x4 zero = {0.f, 0.f, 0.f, 0.f};
    f32x4 d00 = __builtin_amdgcn_mfma_f32_16x16x32_bf16(af0, bf0, zero, 0, 0, 0);
    f32x4 d01 = __builtin_amdgcn_mfma_f32_16x16x32_bf16(af0, bf1, zero, 0, 0, 0);
    f32x4 d10 = __builtin_amdgcn_mfma_f32_16x16x32_bf16(af1, bf0, zero, 0, 0, 0);
    f32x4 d11 = __builtin_amdgcn_mfma_f32_16x16x32_bf16(af1, bf1, zero, 0, 0, 0);

    float zm = fmaxf(fmaxf(MAXD4(d00), MAXD4(d01)), fmaxf(MAXD4(d10), MAXD4(d11)));
    zm = fmaxf(zm, __shfl_xor(zm,  1));
    zm = fmaxf(zm, __shfl_xor(zm,  2));
    zm = fmaxf(zm, __shfl_xor(zm,  4));
    zm = fmaxf(zm, __shfl_xor(zm,  8));
    zm = fmaxf(zm, __shfl_xor(zm, 16));
    zm = fmaxf(zm, __shfl_xor(zm, 32));
    const int eb = __float_as_int(zm) & 0x7f800000;
    const float s = __int_as_float(0x7F000000 - eb);

    // write m89 layout (r9's validated MSTEP write pattern)
#pragma unroll
    for (int t = 0; t < 4; ++t) {
        Mdst[(4*q + t) * 36 + p]           = d00[t] * s;
        Mdst[(4*q + t) * 36 + 16 + p]      = d01[t] * s;
        Mdst[(16 + 4*q + t) * 36 + p]      = d10[t] * s;
        Mdst[(16 + 4*q + t) * 36 + 16 + p] = d11[t] * s;
    }
    return (eb >> 23) - 127;
}

__global__ __launch_bounds__(512, 1) void tt_main_kernel(const int* __restrict__ X,
                                                         const float* __restrict__ Lb,
                                                         const float* __restrict__ Rb,
                                                         float* __restrict__ out)
{
    __shared__ int   idxs[256];
    __shared__ __align__(16) float Ms[15 * 1152];   // 8 seg + 4 L1 + 2 L2 + 1 L3
    __shared__ int   EcA[16];
    __shared__ int   kpart[8];

    const int b    = blockIdx.x;
    const int tid  = threadIdx.x;
    const int wid  = tid >> 6;
    const int lane = tid & 63;

    int ksum = 0;
    if (tid < 256) {
        const int4 xv = ((const int4*)(X + (size_t)b * TT_T))[tid];
        const int m = ((xv.x * 4 + xv.y) * 4 + xv.z) * 4 + xv.w;
        idxs[tid] = m;
        ksum = g_kQ[m];
    }
    if (tid < 16) EcA[tid] = 0;
    ksum += __shfl_xor(ksum,  1);
    ksum += __shfl_xor(ksum,  2);
    ksum += __shfl_xor(ksum,  4);
    ksum += __shfl_xor(ksum,  8);
    ksum += __shfl_xor(ksum, 16);
    ksum += __shfl_xor(ksum, 32);
    if (lane == 0) kpart[wid] = ksum;
    __syncthreads();

    const uint4* qt = g_QT;
    const f32x4 zero = {0.f, 0.f, 0.f, 0.f};

    // ---- segment: quads [32*wid, 32*wid+32), S = P_seg^T ------------------
    const int mbase = 32 * wid;
    const int g = lane >> 4, jj = lane & 15;

    // identity S (sigma form)
    unsigned S0w, S1w, S2w, S3w, S4w, S5w, S6w, S7w;
    {
        const unsigned e0 = ((4*g+0 == jj) ? 0x3F80u : 0u) | ((4*g+1 == jj) ? 0x3F800000u : 0u);
        const unsigned e1 = ((4*g+2 == jj) ? 0x3F80u : 0u) | ((4*g+3 == jj) ? 0x3F800000u : 0u);
        S0w = e0; S1w = e1; S2w = 0u; S3w = 0u;
        S4w = 0u; S5w = 0u; S6w = e0; S7w = e1;
    }

    int   Ecorr = 0;
    float s_apply = 1.0f;
    float* Mseg = Ms + wid * 1152;

    uint4 F0 = qt[idxs[mbase] * 128 + lane];
    uint4 F1 = qt[idxs[mbase] * 128 + 64 + lane];

#pragma unroll 1
    for (int t = 0; t < 32; ++t) {
        uint4 F0n, F1n;
        if (t < 31) {
            const int mn = idxs[mbase + t + 1];
            F0n = qt[mn * 128 + lane];
            F1n = qt[mn * 128 + 64 + lane];
        }
        const bf16x8 af0 = as_bf16x8u(F0);
        const bf16x8 af1 = as_bf16x8u(F1);
        const bf16x8 sb0 = as_bf16x8u(make_uint4(S0w, S1w, S2w, S3w));
        const bf16x8 sb1 = as_bf16x8u(make_uint4(S4w, S5w, S6w, S7w));
        f32x4 d00 = __builtin_amdgcn_mfma_f32_16x16x32_bf16(af0, sb0, zero, 0, 0, 0);
        f32x4 d01 = __builtin_amdgcn_mfma_f32_16x16x32_bf16(af0, sb1, zero, 0, 0, 0);
        f32x4 d10 = __builtin_amdgcn_mfma_f32_16x16x32_bf16(af1, sb0, zero, 0, 0, 0);
        f32x4 d11 = __builtin_amdgcn_mfma_f32_16x16x32_bf16(af1, sb1, zero, 0, 0, 0);

        if (t == 8 || t == 16 || t == 24) {
#pragma unroll
            for (int r = 0; r < 4; ++r) {
                d00[r] *= s_apply; d01[r] *= s_apply;
                d10[r] *= s_apply; d11[r] *= s_apply;
            }
            Ecorr += 127 - ((__float_as_int(s_apply) >> 23) & 0xFF);
        }

        if (t == 31) {
            // sigma-free interface: write physical f32 D to LDS (m89 layout)
#pragma unroll
            for (int u = 0; u < 4; ++u) {
                Mseg[(4*g + u) * 36 + jj]           = d00[u];
                Mseg[(4*g + u) * 36 + 16 + jj]      = d01[u];
                Mseg[(16 + 4*g + u) * 36 + jj]      = d10[u];
                Mseg[(16 + 4*g + u) * 36 + 16 + jj] = d11[u];
            }
        } else {
            if (t == 7 || t == 15 || t == 23) {
                float z = fmaxf(fmaxf(MAXD4(d00), MAXD4(d01)),
                                fmaxf(MAXD4(d10), MAXD4(d11)));
                z = fmaxf(z, __shfl_xor(z,  1));
                z = fmaxf(z, __shfl_xor(z,  2));
                z = fmaxf(z, __shfl_xor(z,  4));
                z = fmaxf(z, __shfl_xor(z,  8));
                z = fmaxf(z, __shfl_xor(z, 16));
                z = fmaxf(z, __shfl_xor(z, 32));
                const int eb = __float_as_int(z) & 0x7f800000;
                s_apply = __int_as_float(0x7F000000 - eb);
            }
            // pack D -> next S (sigma form), zero lane movement
            S0w = pkbf16(d00[0], d00[1]);  S1w = pkbf16(d00[2], d00[3]);
            S2w = pkbf16(d10[0], d10[1]);  S3w = pkbf16(d10[2], d10[3]);
            S4w = pkbf16(d01[0], d01[1]);  S5w = pkbf16(d01[2], d01[3]);
            S6w = pkbf16(d11[0], d11[1]);  S7w = pkbf16(d11[2], d11[3]);
        }
        F0 = F0n; F1 = F1n;
    }

    if (lane == 0) EcA[wid] = Ecorr;
    __syncthreads();

    // ---- tree: 8 -> 4 -> 2 -> 1 (r9-validated mechanics) -------------------
    if (wid < 4) {
        const int ec = tree_node_lds(Ms + (2*wid) * 1152, Ms + (2*wid + 1) * 1152,
                                     Ms + (8 + wid) * 1152, lane);
        if (lane == 0) EcA[8 + wid] = ec;
    }
    __syncthreads();
    if (wid < 2) {
        const int ec = tree_node_lds(Ms + (8 + 2*wid) * 1152, Ms + (8 + 2*wid + 1) * 1152,
                                     Ms + (12 + wid) * 1152, lane);
        if (lane == 0) EcA[12 + wid] = ec;
    }
    __syncthreads();
    int ecL3 = 0;
    if (wid == 0) {
        ecL3 = tree_node_lds(Ms + 12 * 1152, Ms + 13 * 1152, Ms + 14 * 1152, lane);
    }
    __syncthreads();

    // ---- epilogue: out = L^T P R;  S_tot = P^T in Ms[14] -------------------
    if (wid == 0 && lane < 32) {
        const float* Mt = Ms + 14 * 1152;
        // v[r] = sum_c R[c] * S_tot[c][r]  (r9's validated column-read motif)
        float v = 0.f;
#pragma unroll 8
        for (int c2 = 0; c2 < 32; ++c2) v = fmaf(Rb[c2], Mt[c2 * 36 + lane], v);
        float p = v * Lb[lane];
        p += __shfl_xor(p,  1);
        p += __shfl_xor(p,  2);
        p += __shfl_xor(p,  4);
        p += __shfl_xor(p,  8);
        p += __shfl_xor(p, 16);
        if (lane == 0) {
            int S = ecL3;
#pragma unroll
            for (int w = 0; w < 16; ++w) S += EcA[w];
#pragma unroll
            for (int w = 0; w < 8; ++w) S += kpart[w];
            out[b] = 2.0f * ((float)S * 0.6931471805599453f + logf(fabsf(p)));
        }
    }
}

extern "C" void kernel_launch(void* const* d_in, const int* in_sizes, int n_in,
                              void* d_out, int out_size, void* d_ws, size_t ws_size,
                              hipStream_t stream)
{
    const int*   X    = (const int*)d_in[0];
    const float* core = (const float*)d_in[1];
    const float* Lb   = (const float*)d_in[2];
    const float* Rb   = (const float*)d_in[3];
    float* out = (float*)d_out;

    tt_quad_kernel<<<dim3(256), dim3(64), 0, stream>>>(core);
    tt_main_kernel<<<dim3(256), dim3(512), 0, stream>>>(X, Lb, Rb, out);
}

// Round 14
// 21.985 us; speedup vs baseline: 5.3529x; 1.2570x over previous
//
#include <hip/hip_runtime.h>
#include <math.h>

// Tensor-train log-likelihood, B=256, T=1024, d=4, D=32.
// Round 14 = round 13 (PASS, absmax 0) + round-8-validated asm prefetch on
// the segment chain. r12 proved the r10/11 NaN was the tree bit-surgery
// (fixed in r13), NOT the asm loads (passed r4-r9). Ledger: 2 asm
// global_load_dwordx4/step, 4 same-slot banks, 8 outstanding, wait
// vmcnt(6)/step, drain vmcnt(0) before the tree (r3 lesson). Indices:
// one int4 per 4 steps, prefetched one group ahead (r8 pattern).
// Chain math, rescale cadence, tree, epilogue: verbatim r13.

#define TT_B 256
#define TT_T 1024

typedef __attribute__((ext_vector_type(8))) short bf16x8;
typedef __attribute__((ext_vector_type(4))) float f32x4;

// Fragment table: [m][H][lane] = uint4; lane (g=lane>>4, jj=lane&15),
// slot s holds Qs[sigma(g,s)][16H+jj], sigma(g,s)=4g+(s&3)+16*(s>>2).
__device__ uint4 g_QT[256 * 2 * 64];
__device__ int   g_kQ[256];

__device__ __forceinline__ unsigned pkbf16(float lo, float hi)
{
    unsigned r;
    asm volatile("v_cvt_pk_bf16_f32 %0, %1, %2" : "=v"(r) : "v"(lo), "v"(hi));
    return r;
}
__device__ __forceinline__ bf16x8 as_bf16x8(int4 v)
{ union { int4 i; bf16x8 h; } u; u.i = v; return u.h; }
__device__ __forceinline__ bf16x8 as_bf16x8u(uint4 v)
{ union { uint4 i; bf16x8 h; } u; u.i = v; return u.h; }

// ---- quad-product precompute (r13 verbatim) -------------------------------

__device__ __forceinline__ void mm32(const float* __restrict__ AT,
                                     const float* __restrict__ B,
                                     int h, int j, float c[16])
{
#pragma unroll
    for (int r = 0; r < 16; ++r) c[r] = 0.f;
#pragma unroll 4
    for (int k = 0; k < 32; ++k) {
        float bv = B[k * 32 + j];
        const float4* ar = (const float4*)(AT + k * 36 + 16 * h);
        float4 a0 = ar[0], a1 = ar[1], a2 = ar[2], a3 = ar[3];
        c[ 0] = fmaf(a0.x, bv, c[ 0]); c[ 1] = fmaf(a0.y, bv, c[ 1]);
        c[ 2] = fmaf(a0.z, bv, c[ 2]); c[ 3] = fmaf(a0.w, bv, c[ 3]);
        c[ 4] = fmaf(a1.x, bv, c[ 4]); c[ 5] = fmaf(a1.y, bv, c[ 5]);
        c[ 6] = fmaf(a1.z, bv, c[ 6]); c[ 7] = fmaf(a1.w, bv, c[ 7]);
        c[ 8] = fmaf(a2.x, bv, c[ 8]); c[ 9] = fmaf(a2.y, bv, c[ 9]);
        c[10] = fmaf(a2.z, bv, c[10]); c[11] = fmaf(a2.w, bv, c[11]);
        c[12] = fmaf(a3.x, bv, c[12]); c[13] = fmaf(a3.y, bv, c[13]);
        c[14] = fmaf(a3.z, bv, c[14]); c[15] = fmaf(a3.w, bv, c[15]);
    }
}

__device__ __forceinline__ void load_transpose(const float* __restrict__ src,
                                               float* __restrict__ dstT, int lane)
{
    const float4* s4 = (const float4*)src;
    float4 v0 = s4[lane * 4 + 0], v1 = s4[lane * 4 + 1];
    float4 v2 = s4[lane * 4 + 2], v3 = s4[lane * 4 + 3];
    const int ro = lane >> 1;
    const int k0 = (lane & 1) * 16;
    dstT[(k0 +  0) * 36 + ro] = v0.x; dstT[(k0 +  1) * 36 + ro] = v0.y;
    dstT[(k0 +  2) * 36 + ro] = v0.z; dstT[(k0 +  3) * 36 + ro] = v0.w;
    dstT[(k0 +  4) * 36 + ro] = v1.x; dstT[(k0 +  5) * 36 + ro] = v1.y;
    dstT[(k0 +  6) * 36 + ro] = v1.z; dstT[(k0 +  7) * 36 + ro] = v1.w;
    dstT[(k0 +  8) * 36 + ro] = v2.x; dstT[(k0 +  9) * 36 + ro] = v2.y;
    dstT[(k0 + 10) * 36 + ro] = v2.z; dstT[(k0 + 11) * 36 + ro] = v2.w;
    dstT[(k0 + 12) * 36 + ro] = v3.x; dstT[(k0 + 13) * 36 + ro] = v3.y;
    dstT[(k0 + 14) * 36 + ro] = v3.z; dstT[(k0 + 15) * 36 + ro] = v3.w;
}

__device__ __forceinline__ void load_straight(const float* __restrict__ src,
                                              float* __restrict__ dst, int lane)
{
    const float4* s4 = (const float4*)src;
    float4* d4 = (float4*)dst;
    d4[lane * 4 + 0] = s4[lane * 4 + 0];
    d4[lane * 4 + 1] = s4[lane * 4 + 1];
    d4[lane * 4 + 2] = s4[lane * 4 + 2];
    d4[lane * 4 + 3] = s4[lane * 4 + 3];
}

__global__ __launch_bounds__(64) void tt_quad_kernel(const float* __restrict__ core)
{
    __shared__ float AT [32 * 36];
    __shared__ float Bb [32 * 32];
    __shared__ float A2T[32 * 36];
    __shared__ float B2 [32 * 32];
    __shared__ float Qs [32 * 33];

    const int m    = blockIdx.x;
    const int lane = threadIdx.x;
    const int h    = lane >> 5;
    const int j    = lane & 31;

    const int ia = (m >> 6) & 3;
    const int ib = (m >> 4) & 3;
    const int ic = (m >> 2) & 3;
    const int id =  m       & 3;

    float c[16];

    load_transpose(core + ia * 1024, AT, lane);
    load_straight (core + ib * 1024, Bb, lane);
    __syncthreads();
    mm32(AT, Bb, h, j, c);
    __syncthreads();
    {
        float4* dst = (float4*)(A2T + j * 36 + 16 * h);
        dst[0] = make_float4(c[ 0], c[ 1], c[ 2], c[ 3]);
        dst[1] = make_float4(c[ 4], c[ 5], c[ 6], c[ 7]);
        dst[2] = make_float4(c[ 8], c[ 9], c[10], c[11]);
        dst[3] = make_float4(c[12], c[13], c[14], c[15]);
    }
    __syncthreads();

    load_transpose(core + ic * 1024, AT, lane);
    load_straight (core + id * 1024, Bb, lane);
    __syncthreads();
    mm32(AT, Bb, h, j, c);
    __syncthreads();
#pragma unroll
    for (int r = 0; r < 16; ++r) B2[(16 * h + r) * 32 + j] = c[r];
    __syncthreads();

    mm32(A2T, B2, h, j, c);

    // normalize: k = floor(log2(max_j col-abs-sum)), Q *= 2^-k (exact)
    float ssum = 0.f;
#pragma unroll
    for (int r = 0; r < 16; ++r) ssum += fabsf(c[r]);
    ssum += __shfl_xor(ssum, 32);
    float cm = ssum;
    cm = fmaxf(cm, __shfl_xor(cm,  1));
    cm = fmaxf(cm, __shfl_xor(cm,  2));
    cm = fmaxf(cm, __shfl_xor(cm,  4));
    cm = fmaxf(cm, __shfl_xor(cm,  8));
    cm = fmaxf(cm, __shfl_xor(cm, 16));
    const int eb = __float_as_int(cm) & 0x7f800000;
    const float s = __int_as_float(0x7F000000 - eb);
#pragma unroll
    for (int r = 0; r < 16; ++r) c[r] *= s;
    if (lane == 0) g_kQ[m] = (eb >> 23) - 127;

#pragma unroll
    for (int r = 0; r < 16; ++r) Qs[(16 * h + r) * 33 + j] = c[r];
    __syncthreads();

    // emit fragments under sigma(g,s) = 4g + (s&3) + 16*(s>>2)
    const int g  = lane >> 4;
    const int jj = lane & 15;
#pragma unroll
    for (int H = 0; H < 2; ++H) {
        const int cb = 16 * H + jj;
        uint4 wf;
        wf.x = pkbf16(Qs[(4*g+0)*33 + cb],  Qs[(4*g+1)*33 + cb]);
        wf.y = pkbf16(Qs[(4*g+2)*33 + cb],  Qs[(4*g+3)*33 + cb]);
        wf.z = pkbf16(Qs[(16+4*g+0)*33 + cb], Qs[(16+4*g+1)*33 + cb]);
        wf.w = pkbf16(Qs[(16+4*g+2)*33 + cb], Qs[(16+4*g+3)*33 + cb]);
        g_QT[(m * 2 + H) * 64 + lane] = wf;
    }
}

// ---- main kernel -----------------------------------------------------------

#define MAXD4(D) fmaxf(fmaxf(fabsf(D[0]), fabsf(D[1])), fmaxf(fabsf(D[2]), fabsf(D[3])))

// r8-validated asm prefetch: SGPR base + per-lane VGPR offset.
#define LOAD2(UB0, UB1, MIDX) do {                                            \
    const int voff_ = (((MIDX) << 11) | (lane << 4));                         \
    asm volatile("global_load_dwordx4 %0, %1, %2"             : "=v"(UB0) : "v"(voff_), "s"(qtb)); \
    asm volatile("global_load_dwordx4 %0, %1, %2 offset:1024" : "=v"(UB1) : "v"(voff_), "s"(qtb)); \
} while (0)

// One sigma-chain step (r13 math): wait own bank (6 = 3 banks in flight),
// S' = Q^T @ S via 4 MFMA, reload same bank for t+4, pack D -> S (8 pkbf16)
// or (DO_LAST) write f32 D to LDS (m89 layout, sigma-free tree interface).
#define MSTEP(UB0, UB1, MIDX, DO_SCALE, DO_MEAS, DO_LAST) do {                \
    const bf16x8 sb0 = as_bf16x8u(make_uint4(S0w, S1w, S2w, S3w));            \
    const bf16x8 sb1 = as_bf16x8u(make_uint4(S4w, S5w, S6w, S7w));            \
    asm volatile("s_waitcnt vmcnt(6)" ::: "memory");                          \
    __builtin_amdgcn_sched_barrier(0);                                        \
    const bf16x8 af0 = as_bf16x8(UB0);                                        \
    const bf16x8 af1 = as_bf16x8(UB1);                                        \
    f32x4 d00 = __builtin_amdgcn_mfma_f32_16x16x32_bf16(af0, sb0, zero, 0, 0, 0); \
    f32x4 d01 = __builtin_amdgcn_mfma_f32_16x16x32_bf16(af0, sb1, zero, 0, 0, 0); \
    f32x4 d10 = __builtin_amdgcn_mfma_f32_16x16x32_bf16(af1, sb0, zero, 0, 0, 0); \
    f32x4 d11 = __builtin_amdgcn_mfma_f32_16x16x32_bf16(af1, sb1, zero, 0, 0, 0); \
    LOAD2(UB0, UB1, (MIDX));                                                  \
    if (DO_SCALE) {                                                           \
        _Pragma("unroll") for (int r_ = 0; r_ < 4; ++r_) {                    \
            d00[r_] *= s_apply; d01[r_] *= s_apply;                           \
            d10[r_] *= s_apply; d11[r_] *= s_apply;                           \
        }                                                                     \
        Ecorr += 127 - ((__float_as_int(s_apply) >> 23) & 0xFF);              \
    }                                                                         \
    if (DO_MEAS) {                                                            \
        zmeas = fmaxf(fmaxf(MAXD4(d00), MAXD4(d01)),                          \
                      fmaxf(MAXD4(d10), MAXD4(d11)));                         \
    }                                                                         \
    if (DO_LAST) {                                                            \
        _Pragma("unroll") for (int u_ = 0; u_ < 4; ++u_) {                    \
            Mseg[(4*g + u_) * 36 + jj]           = d00[u_];                   \
            Mseg[(4*g + u_) * 36 + 16 + jj]      = d01[u_];                   \
            Mseg[(16 + 4*g + u_) * 36 + jj]      = d10[u_];                   \
            Mseg[(16 + 4*g + u_) * 36 + 16 + jj] = d11[u_];                   \
        }                                                                     \
    } else {                                                                  \
        S0w = pkbf16(d00[0], d00[1]);  S1w = pkbf16(d00[2], d00[3]);          \
        S2w = pkbf16(d10[0], d10[1]);  S3w = pkbf16(d10[2], d10[3]);          \
        S4w = pkbf16(d01[0], d01[1]);  S5w = pkbf16(d01[2], d01[3]);          \
        S6w = pkbf16(d11[0], d11[1]);  S7w = pkbf16(d11[2], d11[3]);          \
    }                                                                         \
} while (0)

// tree node (r13-validated): combined = S_b x S_a, all f32 through LDS.
__device__ __forceinline__ int tree_node_lds(const float* __restrict__ Ma,
                                             const float* __restrict__ Mb,
                                             float* __restrict__ Mdst, int lane)
{
    const int p = lane & 15, q = lane >> 4;
    const float4 a00 = *(const float4*)(Mb + p * 36 + 8 * q);
    const float4 a01 = *(const float4*)(Mb + p * 36 + 8 * q + 4);
    const float4 a10 = *(const float4*)(Mb + (16 + p) * 36 + 8 * q);
    const float4 a11 = *(const float4*)(Mb + (16 + p) * 36 + 8 * q + 4);
    int4 aw0, aw1;
    aw0.x = (int)pkbf16(a00.x, a00.y); aw0.y = (int)pkbf16(a00.z, a00.w);
    aw0.z = (int)pkbf16(a01.x, a01.y); aw0.w = (int)pkbf16(a01.z, a01.w);
    aw1.x = (int)pkbf16(a10.x, a10.y); aw1.y = (int)pkbf16(a10.z, a10.w);
    aw1.z = (int)pkbf16(a11.x, a11.y); aw1.w = (int)pkbf16(a11.z, a11.w);
    int4 bw0, bw1;
    bw0.x = (int)pkbf16(Ma[(8*q+0)*36 + p], Ma[(8*q+1)*36 + p]);
    bw0.y = (int)pkbf16(Ma[(8*q+2)*36 + p], Ma[(8*q+3)*36 + p]);
    bw0.z = (int)pkbf16(Ma[(8*q+4)*36 + p], Ma[(8*q+5)*36 + p]);
    bw0.w = (int)pkbf16(Ma[(8*q+6)*36 + p], Ma[(8*q+7)*36 + p]);
    bw1.x = (int)pkbf16(Ma[(8*q+0)*36 + 16 + p], Ma[(8*q+1)*36 + 16 + p]);
    bw1.y = (int)pkbf16(Ma[(8*q+2)*36 + 16 + p], Ma[(8*q+3)*36 + 16 + p]);
    bw1.z = (int)pkbf16(Ma[(8*q+4)*36 + 16 + p], Ma[(8*q+5)*36 + 16 + p]);
    bw1.w = (int)pkbf16(Ma[(8*q+6)*36 + 16 + p], Ma[(8*q+7)*36 + 16 + p]);

    const bf16x8 af0 = as_bf16x8(aw0), af1 = as_bf16x8(aw1);
    const bf16x8 bf0 = as_bf16x8(bw0), bf1 = as_bf16x8(bw1);
    const f32x4 zero = {0.f, 0.f, 0.f, 0.f};
    f32x4 d00 = __builtin_amdgcn_mfma_f32_16x16x32_bf16(af0, bf0, zero, 0, 0, 0);
    f32x4 d01 = __builtin_amdgcn_mfma_f32_16x16x32_bf16(af0, bf1, zero, 0, 0, 0);
    f32x4 d10 = __builtin_amdgcn_mfma_f32_16x16x32_bf16(af1, bf0, zero, 0, 0, 0);
    f32x4 d11 = __builtin_amdgcn_mfma_f32_16x16x32_bf16(af1, bf1, zero, 0, 0, 0);

    float zm = fmaxf(fmaxf(MAXD4(d00), MAXD4(d01)), fmaxf(MAXD4(d10), MAXD4(d11)));
    zm = fmaxf(zm, __shfl_xor(zm,  1));
    zm = fmaxf(zm, __shfl_xor(zm,  2));
    zm = fmaxf(zm, __shfl_xor(zm,  4));
    zm = fmaxf(zm, __shfl_xor(zm,  8));
    zm = fmaxf(zm, __shfl_xor(zm, 16));
    zm = fmaxf(zm, __shfl_xor(zm, 32));
    const int eb = __float_as_int(zm) & 0x7f800000;
    const float s = __int_as_float(0x7F000000 - eb);
#pragma unroll
    for (int t = 0; t < 4; ++t) {
        Mdst[(4*q + t) * 36 + p]           = d00[t] * s;
        Mdst[(4*q + t) * 36 + 16 + p]      = d01[t] * s;
        Mdst[(16 + 4*q + t) * 36 + p]      = d10[t] * s;
        Mdst[(16 + 4*q + t) * 36 + 16 + p] = d11[t] * s;
    }
    return (eb >> 23) - 127;
}

__global__ __launch_bounds__(512, 1) void tt_main_kernel(const int* __restrict__ X,
                                                         const float* __restrict__ Lb,
                                                         const float* __restrict__ Rb,
                                                         float* __restrict__ out)
{
    __shared__ int   idxs[272];
    __shared__ __align__(16) float Ms[15 * 1152];   // 8 seg + 4 L1 + 2 L2 + 1 L3
    __shared__ int   EcA[16];
    __shared__ int   kpart[8];

    const int b    = blockIdx.x;
    const int tid  = threadIdx.x;
    const int wid  = tid >> 6;
    const int lane = tid & 63;

    int ksum = 0;
    if (tid < 256) {
        const int4 xv = ((const int4*)(X + (size_t)b * TT_T))[tid];
        const int m = ((xv.x * 4 + xv.y) * 4 + xv.z) * 4 + xv.w;
        idxs[tid] = m;
        ksum = g_kQ[m];
    }
    if (tid >= 256 && tid < 272) idxs[tid] = 0;   // pad: tail reloads read 0
    if (tid < 16) EcA[tid] = 0;
    ksum += __shfl_xor(ksum,  1);
    ksum += __shfl_xor(ksum,  2);
    ksum += __shfl_xor(ksum,  4);
    ksum += __shfl_xor(ksum,  8);
    ksum += __shfl_xor(ksum, 16);
    ksum += __shfl_xor(ksum, 32);
    if (lane == 0) kpart[wid] = ksum;
    __syncthreads();

    const uint4* qtb = g_QT;             // compile-time global -> SGPR base
    const f32x4 zero = {0.f, 0.f, 0.f, 0.f};

    // ---- segment: quads [32*wid, 32*wid+32), S = P_seg^T ------------------
    const int base4 = 8 * wid;
    const int4* idxs4 = (const int4*)idxs;
    const int g = lane >> 4, jj = lane & 15;
    float* Mseg = Ms + wid * 1152;

    // identity S (sigma form)
    unsigned S0w, S1w, S2w, S3w, S4w, S5w, S6w, S7w;
    {
        const unsigned e0 = ((4*g+0 == jj) ? 0x3F80u : 0u) | ((4*g+1 == jj) ? 0x3F800000u : 0u);
        const unsigned e1 = ((4*g+2 == jj) ? 0x3F80u : 0u) | ((4*g+3 == jj) ? 0x3F800000u : 0u);
        S0w = e0; S1w = e1; S2w = 0u; S3w = 0u;
        S4w = 0u; S5w = 0u; S6w = e0; S7w = e1;
    }

    int   Ecorr = 0;
    float s_apply = 1.0f, zmeas = 1.0f;

    int4 Ba0, Ba1, Bb0, Bb1, Bc0, Bc1, Bd0, Bd1;
    {
        const int4 m0 = idxs4[base4];        // steps 0..3
        LOAD2(Ba0, Ba1, m0.x);
        LOAD2(Bb0, Bb1, m0.y);
        LOAD2(Bc0, Bc1, m0.z);
        LOAD2(Bd0, Bd1, m0.w);
    }
    int4 mqc = idxs4[base4 + 1];             // reload indices for steps 4..7

#pragma unroll 1
    for (int J = 0; J < 8; ++J) {
        const int4 mq_nx = idxs4[base4 + J + 2];   // J=7 reads zero padding

        const bool sc = (J == 2 || J == 4 || J == 6);   // apply at t=8/16/24
        const bool ms = (J == 1 || J == 3 || J == 5);   // measure at t=7/15/23
        const bool lt = (J == 7);                        // t=31 writes LDS

        MSTEP(Ba0, Ba1, mqc.x, sc, 0, 0);
        MSTEP(Bb0, Bb1, mqc.y, 0, 0, 0);
        MSTEP(Bc0, Bc1, mqc.z, 0, 0, 0);
        MSTEP(Bd0, Bd1, mqc.w, 0, ms, lt);

        if (ms) {
            float z = zmeas;
            z = fmaxf(z, __shfl_xor(z,  1));
            z = fmaxf(z, __shfl_xor(z,  2));
            z = fmaxf(z, __shfl_xor(z,  4));
            z = fmaxf(z, __shfl_xor(z,  8));
            z = fmaxf(z, __shfl_xor(z, 16));
            z = fmaxf(z, __shfl_xor(z, 32));
            const int eb = __float_as_int(z) & 0x7f800000;
            s_apply = __int_as_float(0x7F000000 - eb);
        }
        mqc = mq_nx;
    }

    // drain tail prefetches (idx 0, harmless) before any reuse (r3 lesson)
    asm volatile("s_waitcnt vmcnt(0)" ::: "memory");

    if (lane == 0) EcA[wid] = Ecorr;
    __syncthreads();

    // ---- tree: 8 -> 4 -> 2 -> 1 (r13-validated) ----------------------------
    if (wid < 4) {
        const int ec = tree_node_lds(Ms + (2*wid) * 1152, Ms + (2*wid + 1) * 1152,
                                     Ms + (8 + wid) * 1152, lane);
        if (lane == 0) EcA[8 + wid] = ec;
    }
    __syncthreads();
    if (wid < 2) {
        const int ec = tree_node_lds(Ms + (8 + 2*wid) * 1152, Ms + (8 + 2*wid + 1) * 1152,
                                     Ms + (12 + wid) * 1152, lane);
        if (lane == 0) EcA[12 + wid] = ec;
    }
    __syncthreads();
    int ecL3 = 0;
    if (wid == 0) {
        ecL3 = tree_node_lds(Ms + 12 * 1152, Ms + 13 * 1152, Ms + 14 * 1152, lane);
    }
    __syncthreads();

    // ---- epilogue: out = L^T P R;  S_tot = P^T in Ms[14] -------------------
    if (wid == 0 && lane < 32) {
        const float* Mt = Ms + 14 * 1152;
        float v = 0.f;
#pragma unroll 8
        for (int c2 = 0; c2 < 32; ++c2) v = fmaf(Rb[c2], Mt[c2 * 36 + lane], v);
        float p = v * Lb[lane];
        p += __shfl_xor(p,  1);
        p += __shfl_xor(p,  2);
        p += __shfl_xor(p,  4);
        p += __shfl_xor(p,  8);
        p += __shfl_xor(p, 16);
        if (lane == 0) {
            int S = ecL3;
#pragma unroll
            for (int w = 0; w < 16; ++w) S += EcA[w];
#pragma unroll
            for (int w = 0; w < 8; ++w) S += kpart[w];
            out[b] = 2.0f * ((float)S * 0.6931471805599453f + logf(fabsf(p)));
        }
    }
}

extern "C" void kernel_launch(void* const* d_in, const int* in_sizes, int n_in,
                              void* d_out, int out_size, void* d_ws, size_t ws_size,
                              hipStream_t stream)
{
    const int*   X    = (const int*)d_in[0];
    const float* core = (const float*)d_in[1];
    const float* Lb   = (const float*)d_in[2];
    const float* Rb   = (const float*)d_in[3];
    float* out = (float*)d_out;

    tt_quad_kernel<<<dim3(256), dim3(64), 0, stream>>>(core);
    tt_main_kernel<<<dim3(256), dim3(512), 0, stream>>>(X, Lb, Rb, out);
}

// Round 15
// 21.455 us; speedup vs baseline: 5.4850x; 1.0247x over previous
//
#include <hip/hip_runtime.h>
#include <math.h>

// Tensor-train log-likelihood, B=256, T=1024, d=4, D=32.
// Round 15 = round 14 (PASS, 22.0us) with:
//  (a) quad kernel rewritten on MFMA: Q = Ma@Mb@Mc@Md via 3 calls to the
//      r13-validated tree_node_lds (node(X,Y)=Y@X physical); node rescale
//      exponents accumulate into g_kQ; final col-sum normalization kept.
//  (b) main chain split 16 segments x 16 steps (block=1024, 16 waves);
//      in-chain rescales dropped exactly (||S||_1 < 2^16 bound); 4-level
//      tree (16->8->4->2->1) with ping-pong LDS slot reuse (24 slots).
// Prefetch ledger unchanged (r8-validated): 2 asm loads/step, 4 banks,
// 8 outstanding, vmcnt(6)/step, vmcnt(0) drain (r3 lesson).

#define TT_B 256
#define TT_T 1024

typedef __attribute__((ext_vector_type(8))) short bf16x8;
typedef __attribute__((ext_vector_type(4))) float f32x4;

// Fragment table: [m][H][lane] = uint4; lane (g=lane>>4, jj=lane&15),
// slot s holds Qs[sigma(g,s)][16H+jj], sigma(g,s)=4g+(s&3)+16*(s>>2).
__device__ uint4 g_QT[256 * 2 * 64];
__device__ int   g_kQ[256];

__device__ __forceinline__ unsigned pkbf16(float lo, float hi)
{
    unsigned r;
    asm volatile("v_cvt_pk_bf16_f32 %0, %1, %2" : "=v"(r) : "v"(lo), "v"(hi));
    return r;
}
__device__ __forceinline__ bf16x8 as_bf16x8(int4 v)
{ union { int4 i; bf16x8 h; } u; u.i = v; return u.h; }
__device__ __forceinline__ bf16x8 as_bf16x8u(uint4 v)
{ union { uint4 i; bf16x8 h; } u; u.i = v; return u.h; }

#define MAXD4(D) fmaxf(fmaxf(fabsf(D[0]), fabsf(D[1])), fmaxf(fabsf(D[2]), fabsf(D[3])))

// tree node (r13-validated): node(Ma, Mb) = Mb @ Ma (physical), f32 LDS in
// [32][36] layout both sides, output rescaled by exact pow-2 (max-entry
// exponent), exponent returned.
__device__ __forceinline__ int tree_node_lds(const float* __restrict__ Ma,
                                             const float* __restrict__ Mb,
                                             float* __restrict__ Mdst, int lane)
{
    const int p = lane & 15, q = lane >> 4;
    const float4 a00 = *(const float4*)(Mb + p * 36 + 8 * q);
    const float4 a01 = *(const float4*)(Mb + p * 36 + 8 * q + 4);
    const float4 a10 = *(const float4*)(Mb + (16 + p) * 36 + 8 * q);
    const float4 a11 = *(const float4*)(Mb + (16 + p) * 36 + 8 * q + 4);
    int4 aw0, aw1;
    aw0.x = (int)pkbf16(a00.x, a00.y); aw0.y = (int)pkbf16(a00.z, a00.w);
    aw0.z = (int)pkbf16(a01.x, a01.y); aw0.w = (int)pkbf16(a01.z, a01.w);
    aw1.x = (int)pkbf16(a10.x, a10.y); aw1.y = (int)pkbf16(a10.z, a10.w);
    aw1.z = (int)pkbf16(a11.x, a11.y); aw1.w = (int)pkbf16(a11.z, a11.w);
    int4 bw0, bw1;
    bw0.x = (int)pkbf16(Ma[(8*q+0)*36 + p], Ma[(8*q+1)*36 + p]);
    bw0.y = (int)pkbf16(Ma[(8*q+2)*36 + p], Ma[(8*q+3)*36 + p]);
    bw0.z = (int)pkbf16(Ma[(8*q+4)*36 + p], Ma[(8*q+5)*36 + p]);
    bw0.w = (int)pkbf16(Ma[(8*q+6)*36 + p], Ma[(8*q+7)*36 + p]);
    bw1.x = (int)pkbf16(Ma[(8*q+0)*36 + 16 + p], Ma[(8*q+1)*36 + 16 + p]);
    bw1.y = (int)pkbf16(Ma[(8*q+2)*36 + 16 + p], Ma[(8*q+3)*36 + 16 + p]);
    bw1.z = (int)pkbf16(Ma[(8*q+4)*36 + 16 + p], Ma[(8*q+5)*36 + 16 + p]);
    bw1.w = (int)pkbf16(Ma[(8*q+6)*36 + 16 + p], Ma[(8*q+7)*36 + 16 + p]);

    const bf16x8 af0 = as_bf16x8(aw0), af1 = as_bf16x8(aw1);
    const bf16x8 bf0 = as_bf16x8(bw0), bf1 = as_bf16x8(bw1);
    const f32x4 zero = {0.f, 0.f, 0.f, 0.f};
    f32x4 d00 = __builtin_amdgcn_mfma_f32_16x16x32_bf16(af0, bf0, zero, 0, 0, 0);
    f32x4 d01 = __builtin_amdgcn_mfma_f32_16x16x32_bf16(af0, bf1, zero, 0, 0, 0);
    f32x4 d10 = __builtin_amdgcn_mfma_f32_16x16x32_bf16(af1, bf0, zero, 0, 0, 0);
    f32x4 d11 = __builtin_amdgcn_mfma_f32_16x16x32_bf16(af1, bf1, zero, 0, 0, 0);

    float zm = fmaxf(fmaxf(MAXD4(d00), MAXD4(d01)), fmaxf(MAXD4(d10), MAXD4(d11)));
    zm = fmaxf(zm, __shfl_xor(zm,  1));
    zm = fmaxf(zm, __shfl_xor(zm,  2));
    zm = fmaxf(zm, __shfl_xor(zm,  4));
    zm = fmaxf(zm, __shfl_xor(zm,  8));
    zm = fmaxf(zm, __shfl_xor(zm, 16));
    zm = fmaxf(zm, __shfl_xor(zm, 32));
    const int eb = __float_as_int(zm) & 0x7f800000;
    const float s = __int_as_float(0x7F000000 - eb);
#pragma unroll
    for (int t = 0; t < 4; ++t) {
        Mdst[(4*q + t) * 36 + p]           = d00[t] * s;
        Mdst[(4*q + t) * 36 + 16 + p]      = d01[t] * s;
        Mdst[(16 + 4*q + t) * 36 + p]      = d10[t] * s;
        Mdst[(16 + 4*q + t) * 36 + 16 + p] = d11[t] * s;
    }
    return (eb >> 23) - 127;
}

// ---- quad-product precompute: MFMA version --------------------------------

__global__ __launch_bounds__(64) void tt_quad_kernel(const float* __restrict__ core)
{
    __shared__ __align__(16) float Qb[6 * 1152];   // slots: Ma Mb Mc Md A2 B2

    const int m    = blockIdx.x;
    const int lane = threadIdx.x;

    const int ia = (m >> 6) & 3;
    const int ib = (m >> 4) & 3;
    const int ic = (m >> 2) & 3;
    const int id =  m       & 3;

    // load the 4 core matrices into [32][36] f32 slots
    const int r  = lane >> 1;
    const int hh = (lane & 1) * 16;
#define LOADM(SLOT, IDX) do {                                                 \
        const float4* s4_ = (const float4*)(core + (IDX) * 1024 + r * 32 + hh); \
        float4 v0_ = s4_[0], v1_ = s4_[1], v2_ = s4_[2], v3_ = s4_[3];        \
        float4* d4_ = (float4*)(Qb + (SLOT) * 1152 + r * 36 + hh);            \
        d4_[0] = v0_; d4_[1] = v1_; d4_[2] = v2_; d4_[3] = v3_;               \
    } while (0)
    LOADM(0, ia); LOADM(1, ib); LOADM(2, ic); LOADM(3, id);
#undef LOADM
    __syncthreads();

    // Q = Ma@Mb@Mc@Md via node(X,Y)=Y@X:
    const int e1 = tree_node_lds(Qb + 1 * 1152, Qb + 0 * 1152, Qb + 4 * 1152, lane); // A2 = Ma@Mb
    const int e2 = tree_node_lds(Qb + 3 * 1152, Qb + 2 * 1152, Qb + 5 * 1152, lane); // B2 = Mc@Md
    __syncthreads();
    const int e3 = tree_node_lds(Qb + 5 * 1152, Qb + 4 * 1152, Qb + 0 * 1152, lane); // Q = A2@B2
    __syncthreads();

    // final normalization: k = floor(log2(max_j col-abs-sum)), exact pow-2
    const float* Qf = Qb;                         // slot 0
    const int h = lane >> 5, j = lane & 31;
    float ssum = 0.f;
#pragma unroll
    for (int rr = 0; rr < 16; ++rr) ssum += fabsf(Qf[(16 * h + rr) * 36 + j]);
    ssum += __shfl_xor(ssum, 32);
    float cm = ssum;
    cm = fmaxf(cm, __shfl_xor(cm,  1));
    cm = fmaxf(cm, __shfl_xor(cm,  2));
    cm = fmaxf(cm, __shfl_xor(cm,  4));
    cm = fmaxf(cm, __shfl_xor(cm,  8));
    cm = fmaxf(cm, __shfl_xor(cm, 16));
    const int eb = __float_as_int(cm) & 0x7f800000;
    const float s = __int_as_float(0x7F000000 - eb);
    if (lane == 0) g_kQ[m] = ((eb >> 23) - 127) + e1 + e2 + e3;

    // emit fragments under sigma(g,s) = 4g + (s&3) + 16*(s>>2), scaled by s
    const int g  = lane >> 4;
    const int jj = lane & 15;
#pragma unroll
    for (int H = 0; H < 2; ++H) {
        const int cb = 16 * H + jj;
        uint4 wf;
        wf.x = pkbf16(s * Qf[(4*g+0)*36 + cb],    s * Qf[(4*g+1)*36 + cb]);
        wf.y = pkbf16(s * Qf[(4*g+2)*36 + cb],    s * Qf[(4*g+3)*36 + cb]);
        wf.z = pkbf16(s * Qf[(16+4*g+0)*36 + cb], s * Qf[(16+4*g+1)*36 + cb]);
        wf.w = pkbf16(s * Qf[(16+4*g+2)*36 + cb], s * Qf[(16+4*g+3)*36 + cb]);
        g_QT[(m * 2 + H) * 64 + lane] = wf;
    }
}

// ---- main kernel -----------------------------------------------------------

// r8-validated asm prefetch: SGPR base + per-lane VGPR offset.
#define LOAD2(UB0, UB1, MIDX) do {                                            \
    const int voff_ = (((MIDX) << 11) | (lane << 4));                         \
    asm volatile("global_load_dwordx4 %0, %1, %2"             : "=v"(UB0) : "v"(voff_), "s"(qtb)); \
    asm volatile("global_load_dwordx4 %0, %1, %2 offset:1024" : "=v"(UB1) : "v"(voff_), "s"(qtb)); \
} while (0)

// One sigma-chain step: wait own bank (6 = 3 banks in flight), S' = Q^T @ S
// via 4 MFMA, reload same bank for t+4, pack D -> S (8 pkbf16) or (DO_LAST)
// write f32 D to LDS (m89 layout, sigma-free tree interface). No in-chain
// rescale: ||S||_1 < 2^16 over 16 steps (exact bound, f32-safe).
#define MSTEP(UB0, UB1, MIDX, DO_LAST) do {                                   \
    const bf16x8 sb0 = as_bf16x8u(make_uint4(S0w, S1w, S2w, S3w));            \
    const bf16x8 sb1 = as_bf16x8u(make_uint4(S4w, S5w, S6w, S7w));            \
    asm volatile("s_waitcnt vmcnt(6)" ::: "memory");                          \
    __builtin_amdgcn_sched_barrier(0);                                        \
    const bf16x8 af0 = as_bf16x8(UB0);                                        \
    const bf16x8 af1 = as_bf16x8(UB1);                                        \
    f32x4 d00 = __builtin_amdgcn_mfma_f32_16x16x32_bf16(af0, sb0, zero, 0, 0, 0); \
    f32x4 d01 = __builtin_amdgcn_mfma_f32_16x16x32_bf16(af0, sb1, zero, 0, 0, 0); \
    f32x4 d10 = __builtin_amdgcn_mfma_f32_16x16x32_bf16(af1, sb0, zero, 0, 0, 0); \
    f32x4 d11 = __builtin_amdgcn_mfma_f32_16x16x32_bf16(af1, sb1, zero, 0, 0, 0); \
    LOAD2(UB0, UB1, (MIDX));                                                  \
    if (DO_LAST) {                                                            \
        _Pragma("unroll") for (int u_ = 0; u_ < 4; ++u_) {                    \
            Mseg[(4*g + u_) * 36 + jj]           = d00[u_];                   \
            Mseg[(4*g + u_) * 36 + 16 + jj]      = d01[u_];                   \
            Mseg[(16 + 4*g + u_) * 36 + jj]      = d10[u_];                   \
            Mseg[(16 + 4*g + u_) * 36 + 16 + jj] = d11[u_];                   \
        }                                                                     \
    } else {                                                                  \
        S0w = pkbf16(d00[0], d00[1]);  S1w = pkbf16(d00[2], d00[3]);          \
        S2w = pkbf16(d10[0], d10[1]);  S3w = pkbf16(d10[2], d10[3]);          \
        S4w = pkbf16(d01[0], d01[1]);  S5w = pkbf16(d01[2], d01[3]);          \
        S6w = pkbf16(d11[0], d11[1]);  S7w = pkbf16(d11[2], d11[3]);          \
    }                                                                         \
} while (0)

__global__ __launch_bounds__(1024, 1) void tt_main_kernel(const int* __restrict__ X,
                                                          const float* __restrict__ Lb,
                                                          const float* __restrict__ Rb,
                                                          float* __restrict__ out)
{
    __shared__ __align__(16) int   idxs[272];
    __shared__ __align__(16) float Ms[24 * 1152];  // 16 seg + 8 ping-pong
    __shared__ int   EcA[16];
    __shared__ int   kpart[16];

    const int b    = blockIdx.x;
    const int tid  = threadIdx.x;
    const int wid  = tid >> 6;        // 0..15
    const int lane = tid & 63;

    int ksum = 0;
    if (tid < 256) {
        const int4 xv = ((const int4*)(X + (size_t)b * TT_T))[tid];
        const int m = ((xv.x * 4 + xv.y) * 4 + xv.z) * 4 + xv.w;
        idxs[tid] = m;
        ksum = g_kQ[m];
    }
    if (tid >= 256 && tid < 272) idxs[tid] = 0;   // pad: tail reloads read 0
    if (tid < 16) EcA[tid] = 0;
    ksum += __shfl_xor(ksum,  1);
    ksum += __shfl_xor(ksum,  2);
    ksum += __shfl_xor(ksum,  4);
    ksum += __shfl_xor(ksum,  8);
    ksum += __shfl_xor(ksum, 16);
    ksum += __shfl_xor(ksum, 32);
    if (lane == 0) kpart[wid] = ksum;             // wids >= 4 contribute 0
    __syncthreads();

    const uint4* qtb = g_QT;             // compile-time global -> SGPR base
    const f32x4 zero = {0.f, 0.f, 0.f, 0.f};

    // ---- segment: quads [16*wid, 16*wid+16), S = P_seg^T ------------------
    const int base4 = 4 * wid;
    const int4* idxs4 = (const int4*)idxs;
    const int g = lane >> 4, jj = lane & 15;
    float* Mseg = Ms + wid * 1152;

    // identity S (sigma form)
    unsigned S0w, S1w, S2w, S3w, S4w, S5w, S6w, S7w;
    {
        const unsigned e0 = ((4*g+0 == jj) ? 0x3F80u : 0u) | ((4*g+1 == jj) ? 0x3F800000u : 0u);
        const unsigned e1 = ((4*g+2 == jj) ? 0x3F80u : 0u) | ((4*g+3 == jj) ? 0x3F800000u : 0u);
        S0w = e0; S1w = e1; S2w = 0u; S3w = 0u;
        S4w = 0u; S5w = 0u; S6w = e0; S7w = e1;
    }

    int4 Ba0, Ba1, Bb0, Bb1, Bc0, Bc1, Bd0, Bd1;
    {
        const int4 m0 = idxs4[base4];        // steps 0..3
        LOAD2(Ba0, Ba1, m0.x);
        LOAD2(Bb0, Bb1, m0.y);
        LOAD2(Bc0, Bc1, m0.z);
        LOAD2(Bd0, Bd1, m0.w);
    }
    int4 mqc = idxs4[base4 + 1];             // reload indices for steps 4..7

#pragma unroll 1
    for (int J = 0; J < 4; ++J) {
        const int4 mq_nx = idxs4[base4 + J + 2];   // J=3: next seg / padding

        const bool lt = (J == 3);                  // step 15 writes LDS
        MSTEP(Ba0, Ba1, mqc.x, 0);
        MSTEP(Bb0, Bb1, mqc.y, 0);
        MSTEP(Bc0, Bc1, mqc.z, 0);
        MSTEP(Bd0, Bd1, mqc.w, lt);
        mqc = mq_nx;
    }

    // drain tail prefetches before any reuse (r3 lesson)
    asm volatile("s_waitcnt vmcnt(0)" ::: "memory");
    __syncthreads();

    // ---- tree: 16 -> 8 -> 4 -> 2 -> 1, ping-pong slots ---------------------
    // L1: read seg slots 0..15, write 16..23
    if (wid < 8) {
        const int ec = tree_node_lds(Ms + (2*wid) * 1152, Ms + (2*wid + 1) * 1152,
                                     Ms + (16 + wid) * 1152, lane);
        if (lane == 0) EcA[wid] = ec;
    }
    __syncthreads();
    // L2: read 16..23, write 0..3
    if (wid < 4) {
        const int ec = tree_node_lds(Ms + (16 + 2*wid) * 1152, Ms + (16 + 2*wid + 1) * 1152,
                                     Ms + wid * 1152, lane);
        if (lane == 0) EcA[8 + wid] = ec;
    }
    __syncthreads();
    // L3: read 0..3, write 16..17
    if (wid < 2) {
        const int ec = tree_node_lds(Ms + (2*wid) * 1152, Ms + (2*wid + 1) * 1152,
                                     Ms + (16 + wid) * 1152, lane);
        if (lane == 0) EcA[12 + wid] = ec;
    }
    __syncthreads();
    // L4: read 16..17, write 0
    int ecL4 = 0;
    if (wid == 0) {
        ecL4 = tree_node_lds(Ms + 16 * 1152, Ms + 17 * 1152, Ms, lane);
    }

    // ---- epilogue: out = L^T P R;  S_tot = P^T in slot 0 -------------------
    if (wid == 0 && lane < 32) {
        const float* Mt = Ms;
        float v = 0.f;
#pragma unroll 8
        for (int c2 = 0; c2 < 32; ++c2) v = fmaf(Rb[c2], Mt[c2 * 36 + lane], v);
        float p = v * Lb[lane];
        p += __shfl_xor(p,  1);
        p += __shfl_xor(p,  2);
        p += __shfl_xor(p,  4);
        p += __shfl_xor(p,  8);
        p += __shfl_xor(p, 16);
        if (lane == 0) {
            int S = ecL4;
#pragma unroll
            for (int w = 0; w < 16; ++w) S += EcA[w] + kpart[w];
            out[b] = 2.0f * ((float)S * 0.6931471805599453f + logf(fabsf(p)));
        }
    }
}

extern "C" void kernel_launch(void* const* d_in, const int* in_sizes, int n_in,
                              void* d_out, int out_size, void* d_ws, size_t ws_size,
                              hipStream_t stream)
{
    const int*   X    = (const int*)d_in[0];
    const float* core = (const float*)d_in[1];
    const float* Lb   = (const float*)d_in[2];
    const float* Rb   = (const float*)d_in[3];
    float* out = (float*)d_out;

    tt_quad_kernel<<<dim3(256), dim3(64), 0, stream>>>(core);
    tt_main_kernel<<<dim3(256), dim3(1024), 0, stream>>>(X, Lb, Rb, out);
}

// Round 16
// 21.023 us; speedup vs baseline: 5.5976x; 1.0205x over previous
//
#include <hip/hip_runtime.h>
#include <math.h>

// Tensor-train log-likelihood, B=256, T=1024, d=4, D=32.
// Round 16: SINGLE fused kernel. Per-block LDS pair table (d^2=16 products
// Ma@Mb, built by 16 waves with 4 MFMAs each, rowsum-normalized exact pow-2,
// stored directly as sigma-fragments: the F2 D->S pack formula == the F1
// table A-frag layout, verified symbolically, both r13-validated). Chain:
// 16 waves x 32 pair-steps, operands from LDS (no global loads, no vmcnt,
// no asm loads). Tree (16->8->4->2->1) + epilogue verbatim r15.
// Removes: 2nd kernel, inter-kernel drain, 512KB global table round-trip.
// Rowsum norm gives rigorous ||S||_1 <= 2^32 over 32 steps (no in-chain
// rescale needed). Exponents: 15 tree nodes + per-pair k, summed at end.

#define TT_B 256
#define TT_T 1024

typedef __attribute__((ext_vector_type(8))) short bf16x8;
typedef __attribute__((ext_vector_type(4))) float f32x4;

__device__ __forceinline__ unsigned pkbf16(float lo, float hi)
{
    unsigned r;
    asm volatile("v_cvt_pk_bf16_f32 %0, %1, %2" : "=v"(r) : "v"(lo), "v"(hi));
    return r;
}
__device__ __forceinline__ bf16x8 as_bf16x8(int4 v)
{ union { int4 i; bf16x8 h; } u; u.i = v; return u.h; }
__device__ __forceinline__ bf16x8 as_bf16x8u(uint4 v)
{ union { uint4 i; bf16x8 h; } u; u.i = v; return u.h; }

#define MAXD4(D) fmaxf(fmaxf(fabsf(D[0]), fabsf(D[1])), fmaxf(fabsf(D[2]), fabsf(D[3])))

// tree node (r13-validated, verbatim): node(Ma, Mb) = Mb @ Ma (physical),
// f32 LDS [32][36] both sides, output rescaled by exact pow-2, exp returned.
__device__ __forceinline__ int tree_node_lds(const float* __restrict__ Ma,
                                             const float* __restrict__ Mb,
                                             float* __restrict__ Mdst, int lane)
{
    const int p = lane & 15, q = lane >> 4;
    const float4 a00 = *(const float4*)(Mb + p * 36 + 8 * q);
    const float4 a01 = *(const float4*)(Mb + p * 36 + 8 * q + 4);
    const float4 a10 = *(const float4*)(Mb + (16 + p) * 36 + 8 * q);
    const float4 a11 = *(const float4*)(Mb + (16 + p) * 36 + 8 * q + 4);
    int4 aw0, aw1;
    aw0.x = (int)pkbf16(a00.x, a00.y); aw0.y = (int)pkbf16(a00.z, a00.w);
    aw0.z = (int)pkbf16(a01.x, a01.y); aw0.w = (int)pkbf16(a01.z, a01.w);
    aw1.x = (int)pkbf16(a10.x, a10.y); aw1.y = (int)pkbf16(a10.z, a10.w);
    aw1.z = (int)pkbf16(a11.x, a11.y); aw1.w = (int)pkbf16(a11.z, a11.w);
    int4 bw0, bw1;
    bw0.x = (int)pkbf16(Ma[(8*q+0)*36 + p], Ma[(8*q+1)*36 + p]);
    bw0.y = (int)pkbf16(Ma[(8*q+2)*36 + p], Ma[(8*q+3)*36 + p]);
    bw0.z = (int)pkbf16(Ma[(8*q+4)*36 + p], Ma[(8*q+5)*36 + p]);
    bw0.w = (int)pkbf16(Ma[(8*q+6)*36 + p], Ma[(8*q+7)*36 + p]);
    bw1.x = (int)pkbf16(Ma[(8*q+0)*36 + 16 + p], Ma[(8*q+1)*36 + 16 + p]);
    bw1.y = (int)pkbf16(Ma[(8*q+2)*36 + 16 + p], Ma[(8*q+3)*36 + 16 + p]);
    bw1.z = (int)pkbf16(Ma[(8*q+4)*36 + 16 + p], Ma[(8*q+5)*36 + 16 + p]);
    bw1.w = (int)pkbf16(Ma[(8*q+6)*36 + 16 + p], Ma[(8*q+7)*36 + 16 + p]);

    const bf16x8 af0 = as_bf16x8(aw0), af1 = as_bf16x8(aw1);
    const bf16x8 bf0 = as_bf16x8(bw0), bf1 = as_bf16x8(bw1);
    const f32x4 zero = {0.f, 0.f, 0.f, 0.f};
    f32x4 d00 = __builtin_amdgcn_mfma_f32_16x16x32_bf16(af0, bf0, zero, 0, 0, 0);
    f32x4 d01 = __builtin_amdgcn_mfma_f32_16x16x32_bf16(af0, bf1, zero, 0, 0, 0);
    f32x4 d10 = __builtin_amdgcn_mfma_f32_16x16x32_bf16(af1, bf0, zero, 0, 0, 0);
    f32x4 d11 = __builtin_amdgcn_mfma_f32_16x16x32_bf16(af1, bf1, zero, 0, 0, 0);

    float zm = fmaxf(fmaxf(MAXD4(d00), MAXD4(d01)), fmaxf(MAXD4(d10), MAXD4(d11)));
    zm = fmaxf(zm, __shfl_xor(zm,  1));
    zm = fmaxf(zm, __shfl_xor(zm,  2));
    zm = fmaxf(zm, __shfl_xor(zm,  4));
    zm = fmaxf(zm, __shfl_xor(zm,  8));
    zm = fmaxf(zm, __shfl_xor(zm, 16));
    zm = fmaxf(zm, __shfl_xor(zm, 32));
    const int eb = __float_as_int(zm) & 0x7f800000;
    const float s = __int_as_float(0x7F000000 - eb);
#pragma unroll
    for (int t = 0; t < 4; ++t) {
        Mdst[(4*q + t) * 36 + p]           = d00[t] * s;
        Mdst[(4*q + t) * 36 + 16 + p]      = d01[t] * s;
        Mdst[(16 + 4*q + t) * 36 + p]      = d10[t] * s;
        Mdst[(16 + 4*q + t) * 36 + 16 + p] = d11[t] * s;
    }
    return (eb >> 23) - 127;
}

__global__ __launch_bounds__(1024, 1) void tt_fused_kernel(const int* __restrict__ X,
                                                           const float* __restrict__ core,
                                                           const float* __restrict__ Lb,
                                                           const float* __restrict__ Rb,
                                                           float* __restrict__ out)
{
    __shared__ __align__(16) float Ms[24 * 1152];   // tree slots; 16..19 alias core
    __shared__ __align__(16) uint4 Ptab[2048];      // 16 pairs x 2 halves x 64 lanes
    __shared__ int pidx[544];
    __shared__ int kP[16];
    __shared__ int EcA[16];
    __shared__ int kpart[16];

    const int b    = blockIdx.x;
    const int tid  = threadIdx.x;
    const int wid  = tid >> 6;        // 0..15
    const int lane = tid & 63;
    const int p = lane & 15, q = lane >> 4;
    const int g = q, jj = p;

    // ---- phase 0: parse X -> pair indices; load core -> slots 16..19 ------
    if (tid < 512) {
        const int2 xv = ((const int2*)(X + (size_t)b * TT_T))[tid];
        pidx[tid] = xv.x * 4 + xv.y;
    } else if (tid < 544) {
        pidx[tid] = 0;                // pad for chain lookahead
    }
    if (tid < 16) EcA[tid] = 0;
    if (wid >= 8 && wid < 12) {
        const int mi = wid - 8;
        const int r = lane >> 1, hh = (lane & 1) * 16;
        const float4* s4 = (const float4*)(core + mi * 1024 + r * 32 + hh);
        float4 v0 = s4[0], v1 = s4[1], v2 = s4[2], v3 = s4[3];
        float4* d4 = (float4*)(Ms + (16 + mi) * 1152 + r * 36 + hh);
        d4[0] = v0; d4[1] = v1; d4[2] = v2; d4[3] = v3;
    }
    __syncthreads();

    const f32x4 zero = {0.f, 0.f, 0.f, 0.f};

    // ---- phase 1: pair table. wave w: P = M_{w>>2} @ M_{w&3} ----------------
    // node(param1, param2) = param2 @ param1  =>  param1 = M_{w&3}, param2 = M_{w>>2}
    {
        const float* Pa = Ms + (16 + (wid & 3)) * 1152;   // B-frag source (scalar cols)
        const float* Pb = Ms + (16 + (wid >> 2)) * 1152;  // A-frag source (float4 rows)
        const float4 a00 = *(const float4*)(Pb + p * 36 + 8 * q);
        const float4 a01 = *(const float4*)(Pb + p * 36 + 8 * q + 4);
        const float4 a10 = *(const float4*)(Pb + (16 + p) * 36 + 8 * q);
        const float4 a11 = *(const float4*)(Pb + (16 + p) * 36 + 8 * q + 4);
        int4 aw0, aw1;
        aw0.x = (int)pkbf16(a00.x, a00.y); aw0.y = (int)pkbf16(a00.z, a00.w);
        aw0.z = (int)pkbf16(a01.x, a01.y); aw0.w = (int)pkbf16(a01.z, a01.w);
        aw1.x = (int)pkbf16(a10.x, a10.y); aw1.y = (int)pkbf16(a10.z, a10.w);
        aw1.z = (int)pkbf16(a11.x, a11.y); aw1.w = (int)pkbf16(a11.z, a11.w);
        int4 bw0, bw1;
        bw0.x = (int)pkbf16(Pa[(8*q+0)*36 + p], Pa[(8*q+1)*36 + p]);
        bw0.y = (int)pkbf16(Pa[(8*q+2)*36 + p], Pa[(8*q+3)*36 + p]);
        bw0.z = (int)pkbf16(Pa[(8*q+4)*36 + p], Pa[(8*q+5)*36 + p]);
        bw0.w = (int)pkbf16(Pa[(8*q+6)*36 + p], Pa[(8*q+7)*36 + p]);
        bw1.x = (int)pkbf16(Pa[(8*q+0)*36 + 16 + p], Pa[(8*q+1)*36 + 16 + p]);
        bw1.y = (int)pkbf16(Pa[(8*q+2)*36 + 16 + p], Pa[(8*q+3)*36 + 16 + p]);
        bw1.z = (int)pkbf16(Pa[(8*q+4)*36 + 16 + p], Pa[(8*q+5)*36 + 16 + p]);
        bw1.w = (int)pkbf16(Pa[(8*q+6)*36 + 16 + p], Pa[(8*q+7)*36 + 16 + p]);
        const bf16x8 af0 = as_bf16x8(aw0), af1 = as_bf16x8(aw1);
        const bf16x8 bf0 = as_bf16x8(bw0), bf1 = as_bf16x8(bw1);
        f32x4 d00 = __builtin_amdgcn_mfma_f32_16x16x32_bf16(af0, bf0, zero, 0, 0, 0);
        f32x4 d01 = __builtin_amdgcn_mfma_f32_16x16x32_bf16(af0, bf1, zero, 0, 0, 0);
        f32x4 d10 = __builtin_amdgcn_mfma_f32_16x16x32_bf16(af1, bf0, zero, 0, 0, 0);
        f32x4 d11 = __builtin_amdgcn_mfma_f32_16x16x32_bf16(af1, bf1, zero, 0, 0, 0);

        // rowsum-normalize (exact pow-2): rowsum(r) over P's 32 cols.
        // lane(q,p) holds rows {4q+t} and {16+4q+t}, cols p and 16+p.
        float rs[4], ru[4];
#pragma unroll
        for (int t = 0; t < 4; ++t) {
            rs[t] = fabsf(d00[t]) + fabsf(d01[t]);
            ru[t] = fabsf(d10[t]) + fabsf(d11[t]);
        }
#pragma unroll
        for (int sh = 1; sh <= 8; sh <<= 1) {
#pragma unroll
            for (int t = 0; t < 4; ++t) {
                rs[t] += __shfl_xor(rs[t], sh);
                ru[t] += __shfl_xor(ru[t], sh);
            }
        }
        float mx = fmaxf(fmaxf(fmaxf(rs[0], rs[1]), fmaxf(rs[2], rs[3])),
                         fmaxf(fmaxf(ru[0], ru[1]), fmaxf(ru[2], ru[3])));
        mx = fmaxf(mx, __shfl_xor(mx, 16));
        mx = fmaxf(mx, __shfl_xor(mx, 32));
        const int eb = __float_as_int(mx) & 0x7f800000;
        const float s = __int_as_float(0x7F000000 - eb);
        if (lane == 0) kP[wid] = (eb >> 23) - 127;

        // pack (F2 == table A-frag layout F1, verified) into LDS pair table
        uint4 H0, H1;
        H0.x = pkbf16(d00[0]*s, d00[1]*s);  H0.y = pkbf16(d00[2]*s, d00[3]*s);
        H0.z = pkbf16(d10[0]*s, d10[1]*s);  H0.w = pkbf16(d10[2]*s, d10[3]*s);
        H1.x = pkbf16(d01[0]*s, d01[1]*s);  H1.y = pkbf16(d01[2]*s, d01[3]*s);
        H1.z = pkbf16(d11[0]*s, d11[1]*s);  H1.w = pkbf16(d11[2]*s, d11[3]*s);
        Ptab[wid * 128 + lane]      = H0;
        Ptab[wid * 128 + 64 + lane] = H1;
    }
    __syncthreads();

    // ---- phase 2: per-sequence exponent sum over 512 pairs -----------------
    int ksum = 0;
    if (tid < 512) ksum = kP[pidx[tid]];
    ksum += __shfl_xor(ksum,  1);
    ksum += __shfl_xor(ksum,  2);
    ksum += __shfl_xor(ksum,  4);
    ksum += __shfl_xor(ksum,  8);
    ksum += __shfl_xor(ksum, 16);
    ksum += __shfl_xor(ksum, 32);
    if (lane == 0) kpart[wid] = ksum;    // waves 8..15 contribute 0

    // ---- phase 3: chain. wave w: pairs [32w, 32w+32), S = (prod P)^T -------
    const int base = 32 * wid;
    float* Mseg = Ms + wid * 1152;

    unsigned S0w, S1w, S2w, S3w, S4w, S5w, S6w, S7w;
    {
        const unsigned e0 = ((4*g+0 == jj) ? 0x3F80u : 0u) | ((4*g+1 == jj) ? 0x3F800000u : 0u);
        const unsigned e1 = ((4*g+2 == jj) ? 0x3F80u : 0u) | ((4*g+3 == jj) ? 0x3F800000u : 0u);
        S0w = e0; S1w = e1; S2w = 0u; S3w = 0u;
        S4w = 0u; S5w = 0u; S6w = e0; S7w = e1;
    }

    const int m0 = pidx[base];
    uint4 F0c = Ptab[m0 * 128 + lane];
    uint4 F1c = Ptab[m0 * 128 + 64 + lane];

#pragma unroll 1
    for (int t = 0; t < 32; ++t) {
        const int mn = pidx[base + t + 1];           // t=31 reads pad (0)
        const uint4 F0n = Ptab[mn * 128 + lane];
        const uint4 F1n = Ptab[mn * 128 + 64 + lane];

        const bf16x8 af0 = as_bf16x8u(F0c);
        const bf16x8 af1 = as_bf16x8u(F1c);
        const bf16x8 sb0 = as_bf16x8u(make_uint4(S0w, S1w, S2w, S3w));
        const bf16x8 sb1 = as_bf16x8u(make_uint4(S4w, S5w, S6w, S7w));
        f32x4 d00 = __builtin_amdgcn_mfma_f32_16x16x32_bf16(af0, sb0, zero, 0, 0, 0);
        f32x4 d01 = __builtin_amdgcn_mfma_f32_16x16x32_bf16(af0, sb1, zero, 0, 0, 0);
        f32x4 d10 = __builtin_amdgcn_mfma_f32_16x16x32_bf16(af1, sb0, zero, 0, 0, 0);
        f32x4 d11 = __builtin_amdgcn_mfma_f32_16x16x32_bf16(af1, sb1, zero, 0, 0, 0);

        if (t == 31) {
            // sigma-free interface: physical f32 D to LDS (m89 layout)
#pragma unroll
            for (int u = 0; u < 4; ++u) {
                Mseg[(4*g + u) * 36 + jj]           = d00[u];
                Mseg[(4*g + u) * 36 + 16 + jj]      = d01[u];
                Mseg[(16 + 4*g + u) * 36 + jj]      = d10[u];
                Mseg[(16 + 4*g + u) * 36 + 16 + jj] = d11[u];
            }
        } else {
            S0w = pkbf16(d00[0], d00[1]);  S1w = pkbf16(d00[2], d00[3]);
            S2w = pkbf16(d10[0], d10[1]);  S3w = pkbf16(d10[2], d10[3]);
            S4w = pkbf16(d01[0], d01[1]);  S5w = pkbf16(d01[2], d01[3]);
            S6w = pkbf16(d11[0], d11[1]);  S7w = pkbf16(d11[2], d11[3]);
        }
        F0c = F0n; F1c = F1n;
    }
    __syncthreads();

    // ---- phase 4: tree 16 -> 8 -> 4 -> 2 -> 1, ping-pong slots (r15) -------
    if (wid < 8) {
        const int ec = tree_node_lds(Ms + (2*wid) * 1152, Ms + (2*wid + 1) * 1152,
                                     Ms + (16 + wid) * 1152, lane);
        if (lane == 0) EcA[wid] = ec;
    }
    __syncthreads();
    if (wid < 4) {
        const int ec = tree_node_lds(Ms + (16 + 2*wid) * 1152, Ms + (16 + 2*wid + 1) * 1152,
                                     Ms + wid * 1152, lane);
        if (lane == 0) EcA[8 + wid] = ec;
    }
    __syncthreads();
    if (wid < 2) {
        const int ec = tree_node_lds(Ms + (2*wid) * 1152, Ms + (2*wid + 1) * 1152,
                                     Ms + (16 + wid) * 1152, lane);
        if (lane == 0) EcA[12 + wid] = ec;
    }
    __syncthreads();
    int ecL4 = 0;
    if (wid == 0) {
        ecL4 = tree_node_lds(Ms + 16 * 1152, Ms + 17 * 1152, Ms, lane);
    }

    // ---- phase 5: epilogue: out = L^T P R; S_tot = P^T in slot 0 -----------
    if (wid == 0 && lane < 32) {
        const float* Mt = Ms;
        float v = 0.f;
#pragma unroll 8
        for (int c2 = 0; c2 < 32; ++c2) v = fmaf(Rb[c2], Mt[c2 * 36 + lane], v);
        float pp = v * Lb[lane];
        pp += __shfl_xor(pp,  1);
        pp += __shfl_xor(pp,  2);
        pp += __shfl_xor(pp,  4);
        pp += __shfl_xor(pp,  8);
        pp += __shfl_xor(pp, 16);
        if (lane == 0) {
            int S = ecL4;
#pragma unroll
            for (int w = 0; w < 16; ++w) S += EcA[w] + kpart[w];
            out[b] = 2.0f * ((float)S * 0.6931471805599453f + logf(fabsf(pp)));
        }
    }
}

extern "C" void kernel_launch(void* const* d_in, const int* in_sizes, int n_in,
                              void* d_out, int out_size, void* d_ws, size_t ws_size,
                              hipStream_t stream)
{
    const int*   X    = (const int*)d_in[0];
    const float* core = (const float*)d_in[1];
    const float* Lb   = (const float*)d_in[2];
    const float* Rb   = (const float*)d_in[3];
    float* out = (float*)d_out;

    tt_fused_kernel<<<dim3(256), dim3(1024), 0, stream>>>(X, core, Lb, Rb, out);
}